// Round 6
// baseline (611.369 us; speedup 1.0000x reference)
//
#include <hip/hip_runtime.h>
#include <hip/hip_bf16.h>
#include <stdint.h>

// MPNN latency predictor, MI355X — round 13.
// Budget audit: R8's measured k_msg (138us) vs total (590us) puts the REST of
// the pipeline at ~175us, while a first-principles model of k_node/setup/
// decoder says ~40us. R11/R12 falsified stream-BW and barrier theories inside
// k_msg. The unexplained ~135us lives BETWEEN dispatches (ramp/drain tails of
// 9 steady-state launches + 6 device-drain boundaries per step loop).
// R13: ONE persistent kernel fuses 3x(msg+node)+decoder.
//  * 256 blocks x 512 threads, LDS 100KB -> exactly 1 block/CU, grid == CU
//    count -> all blocks co-resident (safe custom grid barrier).
//  * grid barrier: generation counter, agent-scope __hip_atomic_*, 
//    __threadfence for cross-XCD visibility; __syncthreads (compiler-inserted
//    waitcnt 0) drains each thread's stores before arrival.
//  * msg phase == R12 verbatim (wave-private dbuf staging, counted vmcnt(4));
//    hv strips loaded ONCE for all 3 steps (LDS grown so reduce overlay no
//    longer aliases them). node == R10 k_node at 128 nodes/8 waves.
//    decoder at 128 edges/8 waves.
//  * pre-kernels unchanged; k_scan also zeroes barrier state (ws re-poisoned
//    every run).

#define N_NODES 32768
#define N_EDGES 32768
#define STEPS 3
#define NBLK 256

typedef __attribute__((ext_vector_type(8))) short short8;   // 8 bf16 = 4 VGPRs
typedef __attribute__((ext_vector_type(4))) float float4v;  // MFMA C/D

__device__ __forceinline__ float bf2f(unsigned short u) {
    union { unsigned int i; float f; } v; v.i = ((unsigned int)u) << 16; return v.f;
}
__device__ __forceinline__ unsigned short f2bf(float f) {  // RNE
    union { float f; unsigned int i; } v; v.f = f;
    unsigned int x = v.i;
    return (unsigned short)((x + 0x7fffu + ((x >> 16) & 1u)) >> 16);
}

// async global->LDS, 16B/lane; lds dest = wave-uniform base + lane*16
__device__ __forceinline__ void gload_lds16(const void* g, void* l) {
    __builtin_amdgcn_global_load_lds(
        (__attribute__((address_space(1))) void*)g,
        (__attribute__((address_space(3))) void*)l, 16, 0, 0);
}

// grid barrier: all NBLK blocks co-resident (1/CU by construction).
// __syncthreads drains each thread's memory ops (compiler emits waitcnt 0);
// thread 0 release-fences (L2 writeback), arrives, last block bumps the
// generation; acquire fence on wake.
__device__ __forceinline__ void grid_barrier(unsigned int* bar) {
    __syncthreads();
    if (threadIdx.x == 0) {
        __threadfence();
        unsigned g = __hip_atomic_load(&bar[1], __ATOMIC_RELAXED, __HIP_MEMORY_SCOPE_AGENT);
        unsigned v = __hip_atomic_fetch_add(&bar[0], 1u, __ATOMIC_ACQ_REL, __HIP_MEMORY_SCOPE_AGENT);
        if (v == (unsigned)(NBLK - 1)) {
            __hip_atomic_store(&bar[0], 0u, __ATOMIC_RELAXED, __HIP_MEMORY_SCOPE_AGENT);
            __hip_atomic_store(&bar[1], g + 1u, __ATOMIC_RELEASE, __HIP_MEMORY_SCOPE_AGENT);
        } else {
            while (__hip_atomic_load(&bar[1], __ATOMIC_ACQUIRE, __HIP_MEMORY_SCOPE_AGENT) == g)
                __builtin_amdgcn_s_sleep(8);
        }
        __threadfence();
    }
    __syncthreads();
}

// ===================== fused setup kernel ==================================
__global__ __launch_bounds__(256) void k_setup(
    const float* __restrict__ root, const float* __restrict__ Wih,
    const float* __restrict__ Whh,
    const float* __restrict__ We2, const float* __restrict__ be2,
    const float* __restrict__ Wd1, const float* __restrict__ bd1,
    const float* __restrict__ Wd2,
    const float* __restrict__ x, const float* __restrict__ u,
    const float* __restrict__ Wp, const float* __restrict__ bp,
    const float* __restrict__ ea, const float* __restrict__ We1,
    const float* __restrict__ be1,
    unsigned short* __restrict__ rootTf, unsigned short* __restrict__ wcombf,
    unsigned short* __restrict__ w2tf,
    unsigned short* __restrict__ wd1f, unsigned short* __restrict__ wd2f,
    unsigned short* __restrict__ hb,
    unsigned short* __restrict__ hidT, float* __restrict__ cnts)
{
    int b = blockIdx.x, tid = threadIdx.x;
    if (b < 144) {
        int i = b * 256 + tid;
        if (i < 4096) {
            int j = i & 7, lane = (i >> 3) & 63, g = i >> 9;   // g<8
            int kb = g >> 2, nf = g & 3;
            int o = nf * 16 + (lane & 15);
            int k = kb * 32 + (lane >> 4) * 8 + j;
            rootTf[i] = f2bf(root[k * 64 + o]);
        } else if (i < 4096 + 32768) {
            int t = i - 4096;
            int j = t & 7, lane = (t >> 3) & 63, g = t >> 9;   // g<64
            int kb = g >> 4, nf = g & 15;
            int cp = nf * 16 + (lane & 15);
            int k = kb * 32 + (lane >> 4) * 8 + j;
            float v;
            if (cp < 128)      v = (k < 64) ? Wih[cp * 64 + k] : Whh[cp * 64 + (k - 64)];
            else if (cp < 192) v = (k < 64) ? Wih[cp * 64 + k] : 0.f;
            else               v = (k < 64) ? 0.f : Whh[(cp - 64) * 64 + (k - 64)];
            wcombf[t] = f2bf(v);
        }
    } else if (b < 1184) {
        int t = (b - 144) * 256 + tid;   // t < 266240
        if (t < 65 * 4096) {
            int kk = t >> 12, r = t & 4095;
            int j = r & 7, lane = (r >> 3) & 63, g = r >> 9;  // g<8
            int half = g >> 2, nf = g & 3;
            int o = nf * 16 + (lane & 15);
            int hh = half * 32 + (lane >> 4) * 8 + j;
            float v = (kk < 64) ? We2[((size_t)(hh * 64 + o)) * 64 + kk]
                                : be2[(size_t)hh * 64 + o];
            w2tf[t] = f2bf(v);
        }
    } else if (b < 1232) {
        int i = (b - 1184) * 256 + tid;
        if (i < 10240) {
            int j = i & 7, lane = (i >> 3) & 63, g = i >> 9;  // g<20
            int kb = g >> 2, nf = g & 3;
            int o = nf * 16 + (lane & 15);
            int k = kb * 32 + (lane >> 4) * 8 + j;
            float v = (k < 133) ? Wd1[(size_t)o * 133 + k] : (k == 133 ? bd1[o] : 0.f);
            wd1f[i] = f2bf(v);
        } else if (i < 10240 + 2048) {
            int t = i - 10240;
            int j = t & 7, lane = (t >> 3) & 63, g = t >> 9;  // g<4
            int kb = g >> 1, nf = g & 1;
            int o = nf * 16 + (lane & 15);
            int k = kb * 32 + (lane >> 4) * 8 + j;
            wd2f[t] = f2bf(Wd2[(size_t)o * 64 + k]);
        }
    } else if (b < 9424) {
        int idx = (b - 1232) * 256 + tid;
        int n = idx >> 6, j = idx & 63;
        const float* wr = Wp + j * 23;
        const float* xr = x + (size_t)n * 12;
        float s = bp[j];
#pragma unroll
        for (int i = 0; i < 12; i++) s += xr[i] * wr[i];
#pragma unroll
        for (int i = 0; i < 11; i++) s += u[i] * wr[12 + i];
        hb[idx] = f2bf(tanhf(s));
    } else if (b < 17616) {
        int idx = (b - 9424) * 256 + tid;           // idx < 2^21
        int el = idx & 63, j = (idx >> 6) & 63, eb = idx >> 12;
        int e = eb * 64 + el;                       // lane-varying e -> coalesced
        float s = be1[j];
#pragma unroll
        for (int i = 0; i < 5; i++) s += ea[(size_t)e * 5 + i] * We1[j * 5 + i];
        hidT[(size_t)j * N_EDGES + e] = f2bf(s > 0.f ? s : 0.f);
    } else {
        int idx = (b - 17616) * 1024 + tid * 4;
        if (idx < 32768) {
            float4v z = {0.f, 0.f, 0.f, 0.f};
            *(float4v*)(cnts + idx) = z;
        }
    }
}

__global__ __launch_bounds__(256) void k_counts(
    const int* __restrict__ ei, float* __restrict__ counts)
{
    int i = blockIdx.x * 256 + threadIdx.x;
    if (i < N_EDGES) atomicAdd(&counts[ei[N_EDGES + i]], 1.0f);
}

// one-time exclusive prefix sum of counts -> off[0..N] + woff; zero barrier
__global__ __launch_bounds__(1024) void k_scan(
    const float* __restrict__ cnts, int* __restrict__ off, int* __restrict__ woff,
    unsigned int* __restrict__ bar)
{
    __shared__ int part[1024];
    int t = threadIdx.x;
    if (t == 0) { bar[0] = 0u; bar[1] = 0u; }
    int loc[32];
    int s = 0;
#pragma unroll
    for (int i = 0; i < 32; i++) { loc[i] = s; s += (int)cnts[t * 32 + i]; }
    part[t] = s;
    __syncthreads();
    for (int d = 1; d < 1024; d <<= 1) {
        int y = (t >= d) ? part[t - d] : 0;
        __syncthreads();
        part[t] += y;
        __syncthreads();
    }
    int pre = (t == 0) ? 0 : part[t - 1];
#pragma unroll
    for (int i = 0; i < 32; i++) {
        off[t * 32 + i] = pre + loc[i];
        woff[t * 32 + i] = pre + loc[i];
    }
    if (t == 1023) off[32768] = part[1023];
}

// one-time: place edge ids into dst-sorted slots (32K atomics, once)
__global__ __launch_bounds__(256) void k_scatter(
    const int* __restrict__ ei, int* __restrict__ woff, int* __restrict__ eorder)
{
    int e = blockIdx.x * 256 + threadIdx.x;
    if (e < N_EDGES) {
        int d = ei[N_EDGES + e];
        int slot = atomicAdd(&woff[d], 1);
        eorder[slot] = e;
    }
}

// ===================== persistent fused step kernel ========================
// 256 blocks x 512 threads (8 waves), 1 block/CU (LDS 100KB).
// Per step: [msg: R12 structure] -> gridbar -> [node: 128 nodes] -> gridbar.
// After step 3: [decoder: 128 edges]. LDS overlays:
//   msg stage  : [0,65536)   8 waves x 2 db x 4KB (wave-private)
//   msg reduce : [0,69632)   red[4 kg][128][34] f32
//   hv strips  : [69632,102400)  8 waves x 16 rows x 128 e bf16 (PERSISTENT)
//   node       : m_lds [0,18432) + aggl [18432,53248)
//   decoder    : d1f [0,16384) + d2s [16384,33280)
__global__ __launch_bounds__(512, 2) void k_mega(
    const unsigned short* __restrict__ hidT,  // (64, E) bf16
    unsigned short* __restrict__ hb,          // (N,64) bf16 (in-place updated)
    const unsigned short* __restrict__ w2tf,  // (66*4096) frag-interleaved
    const int* __restrict__ ei,
    float* __restrict__ msgbuf,               // (E,64) f32 dense
    const unsigned short* __restrict__ rootTf,
    const unsigned short* __restrict__ wcombf,
    const int* __restrict__ off, const int* __restrict__ eorder,
    const float* __restrict__ cnts, const float* __restrict__ conv_b,
    const float* __restrict__ bih, const float* __restrict__ bhh,
    const float* __restrict__ ea,
    const unsigned short* __restrict__ wd1f, const unsigned short* __restrict__ wd2f,
    const float* __restrict__ bd2,
    const float* __restrict__ Wd3, const float* __restrict__ bd3,
    float* __restrict__ out,
    unsigned int* __restrict__ bar)
{
    __shared__ __attribute__((aligned(16))) unsigned char smem[102400];
    unsigned short* stg   = (unsigned short*)smem;
    unsigned short* hvl   = (unsigned short*)(smem + 69632);
    float*          red   = (float*)smem;
    unsigned short* m_lds = (unsigned short*)smem;
    float*          aggl  = (float*)(smem + 18432);
    unsigned short* d1f   = (unsigned short*)smem;            // [8][1024]
    float*          d2s   = (float*)(smem + 16384);           // [8][528]

    int tid = threadIdx.x, w = tid >> 6, lane = tid & 63;
    int l15 = lane & 15, quad = lane >> 4;
    int bid = blockIdx.x;
    int kg = w & 3, nfh = w >> 2;
    int ebase = bid * 128;
    int node0 = bid * 128;
    int n_w = 16 + (kg == 3 ? 1 : 0);   // kg3 takes the bias row kk=64

    // ---- hv strips: loaded ONCE, persist across all 3 steps ----
    unsigned short* hvp = hvl + w * 2048;    // my 16 rows x 128 edges
#pragma unroll
    for (int r2 = 0; r2 < 16; r2++) {
        unsigned int v = *((const unsigned int*)(hidT + (size_t)(kg * 16 + r2) * N_EDGES + ebase) + lane);
        *((unsigned int*)hvp + r2 * 64 + lane) = v;
    }

    unsigned short* wbuf = stg + w * 4096;   // 2 db x 2048
    auto stage = [&](int r, int db) {
        const unsigned short* g = w2tf + (size_t)(kg * 16 + r) * 4096;
        unsigned short* d = wbuf + db * 2048;
#pragma unroll
        for (int c = 0; c < 4; c++) {             // c = hh*2 + j (j = nf2)
            int hh = c >> 1, j = c & 1;
            gload_lds16(g + (hh * 4 + nfh * 2 + j) * 512 + lane * 8, d + c * 512);
        }
    };

    for (int step = 0; step < STEPS; step++) {
        // =================== msg phase (R12 structure) =====================
        short8 afr[8][2];
#pragma unroll
        for (int t = 0; t < 8; t++) {
            int src = ei[ebase + t * 16 + l15];
#pragma unroll
            for (int hh = 0; hh < 2; hh++)
                afr[t][hh] = *(const short8*)(hb + (size_t)src * 64 + hh * 32 + quad * 8);
        }
        stage(0, 0);
        stage(1, 1);
        asm volatile("s_waitcnt lgkmcnt(0)" ::: "memory");  // hvp writes done

        float4v acc[8][2] = {};   // [tile][nf2]
        for (int r = 0; r < n_w; r++) {
            int db = r & 1;
            if (r < n_w - 1) { asm volatile("s_waitcnt vmcnt(4)" ::: "memory"); }
            else             { asm volatile("s_waitcnt vmcnt(0)" ::: "memory"); }

            bool bias = (r == 16);
            short8 bfr[2][2];
            const unsigned short* bb = wbuf + db * 2048;
#pragma unroll
            for (int hh = 0; hh < 2; hh++)
#pragma unroll
                for (int j = 0; j < 2; j++)
                    bfr[hh][j] = *(const short8*)(bb + (hh * 2 + j) * 512 + lane * 8);

            unsigned long long hu[8] = {};
            if (!bias) {
#pragma unroll
                for (int t = 0; t < 8; t++)
                    hu[t] = *(const unsigned long long*)(hvp + r * 128 + t * 16 + quad * 4);
            }

            asm volatile("s_waitcnt lgkmcnt(0)" ::: "memory");
            if (r + 2 < n_w) stage(r + 2, db);

#pragma unroll
            for (int t = 0; t < 8; t++) {
                float4v z = {0.f, 0.f, 0.f, 0.f};
                float4v T0 = __builtin_amdgcn_mfma_f32_16x16x32_bf16(afr[t][0], bfr[0][0], z, 0, 0, 0);
                T0 = __builtin_amdgcn_mfma_f32_16x16x32_bf16(afr[t][1], bfr[1][0], T0, 0, 0, 0);
                float4v T1 = __builtin_amdgcn_mfma_f32_16x16x32_bf16(afr[t][0], bfr[0][1], z, 0, 0, 0);
                T1 = __builtin_amdgcn_mfma_f32_16x16x32_bf16(afr[t][1], bfr[1][1], T1, 0, 0, 0);
#pragma unroll
                for (int rr = 0; rr < 4; rr++) {
                    float hvv = bias ? 1.0f : bf2f((unsigned short)(hu[t] >> (16 * rr)));
                    acc[t][0][rr] += hvv * T0[rr];
                    acc[t][1][rr] += hvv * T1[rr];
                }
            }
        }

        // reduce 4 kg partials in 2 nf2-rounds (red overlays stage region)
        int row_r = tid >> 2, cq = tid & 3;
#pragma unroll
        for (int nf2 = 0; nf2 < 2; nf2++) {
            __syncthreads();
#pragma unroll
            for (int t = 0; t < 8; t++)
#pragma unroll
                for (int rr = 0; rr < 4; rr++)
                    red[kg * 4352 + (t * 16 + quad * 4 + rr) * 34 + nfh * 16 + l15] = acc[t][nf2][rr];
            __syncthreads();
            float s[8];
#pragma unroll
            for (int i = 0; i < 8; i++) s[i] = 0.f;
#pragma unroll
            for (int g2 = 0; g2 < 4; g2++) {
                const float* rp = red + g2 * 4352 + row_r * 34 + cq * 8;
#pragma unroll
                for (int i = 0; i < 8; i++) s[i] += rp[i];
            }
            int c34 = cq * 8;
            int gcol = ((c34 >> 4) * 2 + nf2) * 16 + (c34 & 15);
            float* op = msgbuf + (size_t)(ebase + row_r) * 64 + gcol;
            float4v v0 = { s[0], s[1], s[2], s[3] };
            float4v v1 = { s[4], s[5], s[6], s[7] };
            *(float4v*)(op) = v0;
            *(float4v*)(op + 4) = v1;
        }

        grid_barrier(bar);   // msgbuf visible everywhere

        // =================== node phase (128 nodes) ========================
        {
            int nl = tid >> 2, cg = tid & 3;
            int nn = node0 + nl;
            int s0 = off[nn], s1 = off[nn + 1];
            float accg[16] = {};
            for (int sl = s0; sl < s1; sl++) {
                int e = eorder[sl];
                const float* mr = msgbuf + (size_t)e * 64 + cg * 16;
#pragma unroll
                for (int q = 0; q < 4; q++) {
                    float4v v = *(const float4v*)(mr + 4 * q);
#pragma unroll
                    for (int j = 0; j < 4; j++) accg[4 * q + j] += v[j];
                }
            }
#pragma unroll
            for (int k = 0; k < 16; k++) aggl[nl * 68 + cg * 16 + k] = accg[k];
        }
        __syncthreads();

        int row0 = w * 16;
        float4v acc1[4] = {};
        {
            short8 a1[2];
#pragma unroll
            for (int kb = 0; kb < 2; kb++)
                a1[kb] = *(const short8*)(hb + (size_t)(node0 + row0 + l15) * 64 + kb * 32 + quad * 8);
#pragma unroll
            for (int kb = 0; kb < 2; kb++)
#pragma unroll
                for (int nf = 0; nf < 4; nf++) {
                    short8 b = *(const short8*)(rootTf + (size_t)((kb * 4 + nf) * 64 + lane) * 8);
                    acc1[nf] = __builtin_amdgcn_mfma_f32_16x16x32_bf16(a1[kb], b, acc1[nf], 0, 0, 0);
                }
        }
#pragma unroll
        for (int rr = 0; rr < 4; rr++) {
            int nl = row0 + quad * 4 + rr;
            float cnt = cnts[node0 + nl]; if (cnt < 1.f) cnt = 1.f;
            float rcp = 1.f / cnt;
#pragma unroll
            for (int nf = 0; nf < 4; nf++) {
                int c = nf * 16 + l15;
                float av = aggl[nl * 68 + c];
                float mv = av * rcp + acc1[nf][rr] + conv_b[c];
                m_lds[nl * 72 + c] = f2bf(mv > 0.f ? mv : 0.f);
            }
        }
        __syncthreads();

        float4v acc2[16] = {};
#pragma unroll
        for (int kb = 0; kb < 4; kb++) {
            short8 a2;
            if (kb < 2)
                a2 = *(const short8*)(m_lds + (row0 + l15) * 72 + kb * 32 + quad * 8);
            else
                a2 = *(const short8*)(hb + (size_t)(node0 + row0 + l15) * 64 + (kb - 2) * 32 + quad * 8);
#pragma unroll
            for (int nf = 0; nf < 16; nf++) {
                short8 b = *(const short8*)(wcombf + (size_t)((kb * 16 + nf) * 64 + lane) * 8);
                acc2[nf] = __builtin_amdgcn_mfma_f32_16x16x32_bf16(a2, b, acc2[nf], 0, 0, 0);
            }
        }

#pragma unroll
        for (int nf0 = 0; nf0 < 4; nf0++) {
            int c = nf0 * 16 + l15;
            float br = bih[c] + bhh[c];
            float bz = bih[64 + c] + bhh[64 + c];
            float bni = bih[128 + c], bnh = bhh[128 + c];
#pragma unroll
            for (int rr = 0; rr < 4; rr++) {
                int node = node0 + row0 + quad * 4 + rr;
                float gr = 1.f / (1.f + __expf(-(acc2[nf0][rr] + br)));
                float gz = 1.f / (1.f + __expf(-(acc2[nf0 + 4][rr] + bz)));
                float ng = tanhf(acc2[nf0 + 8][rr] + bni + gr * (acc2[nf0 + 12][rr] + bnh));
                float ho = bf2f(hb[(size_t)node * 64 + c]);
                float hn = (1.f - gz) * ng + gz * ho;
                hb[(size_t)node * 64 + c] = f2bf(hn);
            }
        }

        grid_barrier(bar);   // hb visible everywhere
    }

    // ====================== decoder phase (128 edges) ======================
    {
        int eb_d = bid * 128 + w * 16;
        int e = eb_d + l15;
        int src = ei[e], dst = ei[N_EDGES + e];

        short8 a[5];
#pragma unroll
        for (int kb = 0; kb < 2; kb++) {
            a[kb]     = *(const short8*)(hb + (size_t)src * 64 + kb * 32 + quad * 8);
            a[2 + kb] = *(const short8*)(hb + (size_t)dst * 64 + kb * 32 + quad * 8);
        }
        {
            union { short8 v; unsigned short u[8]; } tea;
#pragma unroll
            for (int j = 0; j < 8; j++) {
                float vv = 0.f;
                if (quad == 0) vv = (j < 5) ? ea[(size_t)e * 5 + j] : (j == 5 ? 1.f : 0.f);
                tea.u[j] = f2bf(vv);
            }
            a[4] = tea.v;
        }

        float4v acc1[4] = {};
#pragma unroll
        for (int kb = 0; kb < 5; kb++)
#pragma unroll
            for (int nf = 0; nf < 4; nf++) {
                short8 b = *(const short8*)(wd1f + (size_t)((kb * 4 + nf) * 64 + lane) * 8);
                acc1[nf] = __builtin_amdgcn_mfma_f32_16x16x32_bf16(a[kb], b, acc1[nf], 0, 0, 0);
            }
#pragma unroll
        for (int nf = 0; nf < 4; nf++) {
            int kbp = nf >> 1;
            int lanep_hi = ((nf & 1) * 2 + (l15 >> 3)) * 16;
            int jp = l15 & 7;
#pragma unroll
            for (int r = 0; r < 4; r++) {
                float v = acc1[nf][r];
                d1f[w * 1024 + kbp * 512 + (lanep_hi + quad * 4 + r) * 8 + jp] = f2bf(v > 0.f ? v : 0.f);
            }
        }
        float4v acc2[2] = {};
#pragma unroll
        for (int kb = 0; kb < 2; kb++) {
            short8 a2 = *(const short8*)(&d1f[w * 1024 + kb * 512 + lane * 8]);
#pragma unroll
            for (int nf = 0; nf < 2; nf++) {
                short8 b = *(const short8*)(wd2f + (size_t)((kb * 2 + nf) * 64 + lane) * 8);
                acc2[nf] = __builtin_amdgcn_mfma_f32_16x16x32_bf16(a2, b, acc2[nf], 0, 0, 0);
            }
        }
#pragma unroll
        for (int nf = 0; nf < 2; nf++) {
            int c = nf * 16 + l15;
            float bias = bd2[c];
#pragma unroll
            for (int r = 0; r < 4; r++) {
                float v = acc2[nf][r] + bias;
                d2s[w * 528 + (quad * 4 + r) * 33 + c] = v > 0.f ? v : 0.f;
            }
        }
        {
            int e_l = lane >> 2, t = lane & 3;
            float s = bd3[t];
            const float* w3 = Wd3 + t * 32;
            const float* dr = &d2s[w * 528 + e_l * 33];
#pragma unroll
            for (int k = 0; k < 32; k++) s += w3[k] * dr[k];
            out[(size_t)(eb_d + e_l) * 4 + t] = s;
        }
    }
}

extern "C" void kernel_launch(void* const* d_in, const int* in_sizes, int n_in,
                              void* d_out, int out_size, void* d_ws, size_t ws_size,
                              hipStream_t stream)
{
    const float* x      = (const float*)d_in[0];
    const int*   ei     = (const int*)d_in[1];
    const float* ea     = (const float*)d_in[2];
    const float* u      = (const float*)d_in[3];
    const float* Wp     = (const float*)d_in[4];
    const float* bp     = (const float*)d_in[5];
    const float* We1    = (const float*)d_in[6];
    const float* be1    = (const float*)d_in[7];
    const float* We2    = (const float*)d_in[8];
    const float* be2    = (const float*)d_in[9];
    const float* root   = (const float*)d_in[10];
    const float* conv_b = (const float*)d_in[11];
    const float* Wih    = (const float*)d_in[12];
    const float* bih    = (const float*)d_in[13];
    const float* Whh    = (const float*)d_in[14];
    const float* bhh    = (const float*)d_in[15];
    const float* Wd1    = (const float*)d_in[16];
    const float* bd1    = (const float*)d_in[17];
    const float* Wd2    = (const float*)d_in[18];
    const float* bd2    = (const float*)d_in[19];
    const float* Wd3    = (const float*)d_in[20];
    const float* bd3    = (const float*)d_in[21];
    float* out = (float*)d_out;

    char* ws = (char*)d_ws;
    size_t off_b = 0;
    auto take = [&](size_t bytes) -> char* {
        char* p = ws + off_b; off_b = (off_b + bytes + 255) & ~(size_t)255; return p;
    };
    unsigned short* hb     = (unsigned short*)take((size_t)N_NODES * 64 * 2);
    unsigned short* hidT   = (unsigned short*)take((size_t)N_EDGES * 64 * 2);
    float*          msgbuf = (float*)take((size_t)N_EDGES * 64 * 4);
    float*          cnts   = (float*)take((size_t)N_NODES * 4);
    int*            off    = (int*)take((size_t)(N_NODES + 1) * 4);
    int*            woff   = (int*)take((size_t)N_NODES * 4);
    int*            eorder = (int*)take((size_t)N_EDGES * 4);
    unsigned int*   bar    = (unsigned int*)take(256);
    unsigned short* w2tf   = (unsigned short*)take((size_t)66 * 4096 * 2);  // +1 pad blk
    unsigned short* rootTf = (unsigned short*)take((size_t)4096 * 2);
    unsigned short* wcombf = (unsigned short*)take((size_t)32768 * 2);
    unsigned short* wd1f   = (unsigned short*)take((size_t)10240 * 2);
    unsigned short* wd2f   = (unsigned short*)take((size_t)2048 * 2);
    (void)ws_size;

    k_setup<<<17648, 256, 0, stream>>>(root, Wih, Whh, We2, be2, Wd1, bd1, Wd2,
                                       x, u, Wp, bp, ea, We1, be1,
                                       rootTf, wcombf, w2tf, wd1f, wd2f,
                                       hb, hidT, cnts);
    k_counts<<<128, 256, 0, stream>>>(ei, cnts);
    k_scan<<<1, 1024, 0, stream>>>(cnts, off, woff, bar);
    k_scatter<<<128, 256, 0, stream>>>(ei, woff, eorder);

    k_mega<<<NBLK, 512, 0, stream>>>(hidT, hb, w2tf, ei, msgbuf,
                                     rootTf, wcombf, off, eorder, cnts,
                                     conv_b, bih, bhh, ea, wd1f, wd2f,
                                     bd2, Wd3, bd3, out, bar);
}

// Round 7
// 313.077 us; speedup vs baseline: 1.9528x; 1.9528x over previous
//
#include <hip/hip_runtime.h>
#include <hip/hip_bf16.h>
#include <stdint.h>

// MPNN latency predictor, MI355X — round 14.
// R13 post-mortem: persistent kernel's grid-barrier fences (device-scope) are
// L2 writeback+invalidate on gfx950 -> FETCH_SIZE 6MB -> 206MB, kernel ran at
// HBM refetch speed. Persistence abandoned; multi-dispatch keeps L2 residency.
// Budget model (consistent R7-R12): ~168us = 4x42us workspace-poison fills
// (fixed, not ours), ~92us = our kernels. msg proved latency-bound (stream-
// halving R12 and barrier-removal both neutral; only 8 waves/CU hiding L2
// latency of staged loads).
// R14: (1) msg at 16 waves/CU: 64 edges/block x 512 blocks, R12 wave-split
// (kg x nfh), wave-private dbuf staging, LDS 72KB -> 2 blocks/CU (was 1).
// hv strip SHARED across nfh (8KB, one prologue barrier only). (2) merge
// counts+scan+scatter into one 1-block kernel (LDS counts + LDS atomics).

#define N_NODES 32768
#define N_EDGES 32768
#define STEPS 3

typedef __attribute__((ext_vector_type(8))) short short8;   // 8 bf16 = 4 VGPRs
typedef __attribute__((ext_vector_type(4))) float float4v;  // MFMA C/D

__device__ __forceinline__ float bf2f(unsigned short u) {
    union { unsigned int i; float f; } v; v.i = ((unsigned int)u) << 16; return v.f;
}
__device__ __forceinline__ unsigned short f2bf(float f) {  // RNE
    union { float f; unsigned int i; } v; v.f = f;
    unsigned int x = v.i;
    return (unsigned short)((x + 0x7fffu + ((x >> 16) & 1u)) >> 16);
}

// async global->LDS, 16B/lane; lds dest = wave-uniform base + lane*16
__device__ __forceinline__ void gload_lds16(const void* g, void* l) {
    __builtin_amdgcn_global_load_lds(
        (__attribute__((address_space(1))) void*)g,
        (__attribute__((address_space(3))) void*)l, 16, 0, 0);
}

// ===================== fused setup kernel ==================================
// blockIdx segments:
//  [0,144)       rootTf (4096) + wcombf (32768)      — frag-interleaved
//  [144,1184)    w2tf (266240 valid + 4096 pad)       — frag-interleaved
//  [1184,1232)   wd1f (10240) + wd2f (2048)           — frag-interleaved
//  [1232,9424)   proj: hb = bf16(tanh([x,u]@Wp^T+bp))
//  [9424,17616)  edge hidden TRANSPOSED: hidT[j][e] = relu(ea@We1^T+be1)
__global__ __launch_bounds__(256) void k_setup(
    const float* __restrict__ root, const float* __restrict__ Wih,
    const float* __restrict__ Whh,
    const float* __restrict__ We2, const float* __restrict__ be2,
    const float* __restrict__ Wd1, const float* __restrict__ bd1,
    const float* __restrict__ Wd2,
    const float* __restrict__ x, const float* __restrict__ u,
    const float* __restrict__ Wp, const float* __restrict__ bp,
    const float* __restrict__ ea, const float* __restrict__ We1,
    const float* __restrict__ be1,
    unsigned short* __restrict__ rootTf, unsigned short* __restrict__ wcombf,
    unsigned short* __restrict__ w2tf,
    unsigned short* __restrict__ wd1f, unsigned short* __restrict__ wd2f,
    unsigned short* __restrict__ hb,
    unsigned short* __restrict__ hidT)
{
    int b = blockIdx.x, tid = threadIdx.x;
    if (b < 144) {
        int i = b * 256 + tid;
        if (i < 4096) {
            int j = i & 7, lane = (i >> 3) & 63, g = i >> 9;   // g<8
            int kb = g >> 2, nf = g & 3;
            int o = nf * 16 + (lane & 15);
            int k = kb * 32 + (lane >> 4) * 8 + j;
            rootTf[i] = f2bf(root[k * 64 + o]);
        } else if (i < 4096 + 32768) {
            int t = i - 4096;
            int j = t & 7, lane = (t >> 3) & 63, g = t >> 9;   // g<64
            int kb = g >> 4, nf = g & 15;
            int cp = nf * 16 + (lane & 15);
            int k = kb * 32 + (lane >> 4) * 8 + j;
            float v;
            if (cp < 128)      v = (k < 64) ? Wih[cp * 64 + k] : Whh[cp * 64 + (k - 64)];
            else if (cp < 192) v = (k < 64) ? Wih[cp * 64 + k] : 0.f;
            else               v = (k < 64) ? 0.f : Whh[(cp - 64) * 64 + (k - 64)];
            wcombf[t] = f2bf(v);
        }
    } else if (b < 1184) {
        int t = (b - 144) * 256 + tid;   // t < 266240
        if (t < 65 * 4096) {
            int kk = t >> 12, r = t & 4095;
            int j = r & 7, lane = (r >> 3) & 63, g = r >> 9;  // g<8
            int half = g >> 2, nf = g & 3;
            int o = nf * 16 + (lane & 15);
            int hh = half * 32 + (lane >> 4) * 8 + j;
            float v = (kk < 64) ? We2[((size_t)(hh * 64 + o)) * 64 + kk]
                                : be2[(size_t)hh * 64 + o];
            w2tf[t] = f2bf(v);
        }
    } else if (b < 1232) {
        int i = (b - 1184) * 256 + tid;
        if (i < 10240) {
            int j = i & 7, lane = (i >> 3) & 63, g = i >> 9;  // g<20
            int kb = g >> 2, nf = g & 3;
            int o = nf * 16 + (lane & 15);
            int k = kb * 32 + (lane >> 4) * 8 + j;
            float v = (k < 133) ? Wd1[(size_t)o * 133 + k] : (k == 133 ? bd1[o] : 0.f);
            wd1f[i] = f2bf(v);
        } else if (i < 10240 + 2048) {
            int t = i - 10240;
            int j = t & 7, lane = (t >> 3) & 63, g = t >> 9;  // g<4
            int kb = g >> 1, nf = g & 1;
            int o = nf * 16 + (lane & 15);
            int k = kb * 32 + (lane >> 4) * 8 + j;
            wd2f[t] = f2bf(Wd2[(size_t)o * 64 + k]);
        }
    } else if (b < 9424) {
        int idx = (b - 1232) * 256 + tid;
        int n = idx >> 6, j = idx & 63;
        const float* wr = Wp + j * 23;
        const float* xr = x + (size_t)n * 12;
        float s = bp[j];
#pragma unroll
        for (int i = 0; i < 12; i++) s += xr[i] * wr[i];
#pragma unroll
        for (int i = 0; i < 11; i++) s += u[i] * wr[12 + i];
        hb[idx] = f2bf(tanhf(s));
    } else {
        int idx = (b - 9424) * 256 + tid;           // idx < 2^21
        int el = idx & 63, j = (idx >> 6) & 63, eb = idx >> 12;
        int e = eb * 64 + el;                       // lane-varying e -> coalesced
        float s = be1[j];
#pragma unroll
        for (int i = 0; i < 5; i++) s += ea[(size_t)e * 5 + i] * We1[j * 5 + i];
        hidT[(size_t)j * N_EDGES + e] = f2bf(s > 0.f ? s : 0.f);
    }
}

// ===================== merged graph-CSR kernel =============================
// 1 block x 1024 threads. counts (LDS, 128KB) -> scan -> scatter. Replaces
// k_counts + k_scan + k_scatter (3 launches) and setup's cnts-zero segment.
__global__ __launch_bounds__(1024) void k_graph(
    const int* __restrict__ ei, int* __restrict__ off,
    float* __restrict__ cnts, int* __restrict__ eorder)
{
    __shared__ int cnt[N_NODES];     // 128 KB
    __shared__ int part[1024];
    int t = threadIdx.x;
#pragma unroll
    for (int i = 0; i < 32; i++) cnt[t + i * 1024] = 0;
    __syncthreads();
#pragma unroll
    for (int i = 0; i < 32; i++) {
        int e = t + i * 1024;                      // coalesced
        atomicAdd(&cnt[ei[N_EDGES + e]], 1);
    }
    __syncthreads();
    // scan: thread t owns nodes t*32..+31
    int loc[32]; int s = 0;
#pragma unroll
    for (int i = 0; i < 32; i++) { loc[i] = s; s += cnt[t * 32 + i]; }
    part[t] = s;
    __syncthreads();
    for (int d = 1; d < 1024; d <<= 1) {
        int y = (t >= d) ? part[t - d] : 0;
        __syncthreads();
        part[t] += y;
        __syncthreads();
    }
    int pre = (t == 0) ? 0 : part[t - 1];
    int base[32];
#pragma unroll
    for (int i = 0; i < 32; i++) {
        int n = t * 32 + i;
        base[i] = pre + loc[i];
        off[n] = base[i];
        cnts[n] = (float)cnt[n];
    }
    if (t == 1023) off[N_NODES] = N_EDGES;
    __syncthreads();                 // all cnt reads done before overwrite
#pragma unroll
    for (int i = 0; i < 32; i++) cnt[t * 32 + i] = base[i];   // cnt -> cursor
    __syncthreads();
    // scatter
#pragma unroll
    for (int i = 0; i < 32; i++) {
        int e = t + i * 1024;
        int d = ei[N_EDGES + e];
        int slot = atomicAdd(&cnt[d], 1);
        eorder[slot] = e;
    }
}

// ===================== fused msg GEMM ======================================
// 512 blocks x 512 threads = 8 waves: wave = nfh*4 + kg. 64 edges/block.
// kg in {0..3}: kk-slice kg*16..+15 (kg=3 also kk=64 bias row).
// nfh in {0,1}: output col-half. Wave-private staged slice (4KB/kk),
// double-buffered, counted vmcnt(4), ZERO loop barriers.
// LDS 72KB -> 2 blocks/CU -> 16 waves/CU (2x every prior variant: msg is
// latency-bound, TLP is the lever). hv strip SHARED across nfh (one
// prologue barrier). Epilogue: 2 nf2-rounds LDS reduce over 4 kg partials.
__global__ __launch_bounds__(512, 4) void k_msg_fused(
    const unsigned short* __restrict__ hidT,  // (64, E) bf16
    const unsigned short* __restrict__ hb,    // (N,64) bf16
    const unsigned short* __restrict__ w2tf,  // (66*4096) frag-interleaved
    const int* __restrict__ ei,
    float* __restrict__ msgbuf)               // (E,64) f32 dense
{
    // LDS: [0,65536)      stage: 8 waves x 2 db x 2048 ushort (4KB slices)
    //      [65536,73728)  hvl: 64 kk x 64 e bf16 (shared)
    //      reduce overlay on stage: red[4 kg][64 row][34] f32 = 34816B
    __shared__ __attribute__((aligned(16))) unsigned char smem[73728];
    unsigned short* stg = (unsigned short*)smem;
    unsigned short* hvl = (unsigned short*)(smem + 65536);
    float* red = (float*)smem;

    int tid = threadIdx.x, w = tid >> 6, lane = tid & 63;
    int l15 = lane & 15, quad = lane >> 4;
    int kg = w & 3, nfh = w >> 2;
    int ebase = blockIdx.x * 64;
    int n_w = 16 + (kg == 3 ? 1 : 0);   // kg3 takes the bias row kk=64

    // ---- hv strip (shared): wave w loads rows w*8..w*8+7 ----
#pragma unroll
    for (int i = 0; i < 8; i++) {
        int row = w * 8 + i;
        hvl[row * 64 + lane] = hidT[(size_t)row * N_EDGES + ebase + lane];
    }
    __syncthreads();   // hv visible to all waves (one-time; drains vm+lgkm)

    // ---- static A-frags: 4 edge-tiles x 2 K-halves of h[src] (bf16) ----
    short8 afr[4][2];
#pragma unroll
    for (int t = 0; t < 4; t++) {
        int src = ei[ebase + t * 16 + l15];
#pragma unroll
        for (int hh = 0; hh < 2; hh++)
            afr[t][hh] = *(const short8*)(hb + (size_t)src * 64 + hh * 32 + quad * 8);
    }

    unsigned short* wbuf = stg + w * 4096;   // 2 db x 2048
    // stage kk-row (kg*16+r)'s 4 frag-groups for my nf-half into wbuf[db]
    auto stage = [&](int r, int db) {
        const unsigned short* g = w2tf + (size_t)(kg * 16 + r) * 4096;
        unsigned short* d = wbuf + db * 2048;
#pragma unroll
        for (int c = 0; c < 4; c++) {             // c = hh*2 + j (j = nf2)
            int hh = c >> 1, j = c & 1;
            gload_lds16(g + (hh * 4 + nfh * 2 + j) * 512 + lane * 8, d + c * 512);
        }
    };

    stage(0, 0);
    stage(1, 1);

    float4v acc[4][2] = {};   // [tile][nf2]
    for (int r = 0; r < n_w; r++) {
        int db = r & 1;
        // stage r complete; stage r+1's 4 loads may remain in flight
        if (r < n_w - 1) { asm volatile("s_waitcnt vmcnt(4)" ::: "memory"); }
        else             { asm volatile("s_waitcnt vmcnt(0)" ::: "memory"); }

        bool bias = (r == 16);
        short8 bfr[2][2];
        const unsigned short* bb = wbuf + db * 2048;
#pragma unroll
        for (int hh = 0; hh < 2; hh++)
#pragma unroll
            for (int j = 0; j < 2; j++)
                bfr[hh][j] = *(const short8*)(bb + (hh * 2 + j) * 512 + lane * 8);

        unsigned long long hu[4] = {};
        if (!bias) {
#pragma unroll
            for (int t = 0; t < 4; t++)
                hu[t] = *(const unsigned long long*)(hvl + (kg * 16 + r) * 64 + t * 16 + quad * 4);
        }

        asm volatile("s_waitcnt lgkmcnt(0)" ::: "memory");  // my LDS reads done
        if (r + 2 < n_w) stage(r + 2, db);

#pragma unroll
        for (int t = 0; t < 4; t++) {
            float4v z = {0.f, 0.f, 0.f, 0.f};
            float4v T0 = __builtin_amdgcn_mfma_f32_16x16x32_bf16(afr[t][0], bfr[0][0], z, 0, 0, 0);
            T0 = __builtin_amdgcn_mfma_f32_16x16x32_bf16(afr[t][1], bfr[1][0], T0, 0, 0, 0);
            float4v T1 = __builtin_amdgcn_mfma_f32_16x16x32_bf16(afr[t][0], bfr[0][1], z, 0, 0, 0);
            T1 = __builtin_amdgcn_mfma_f32_16x16x32_bf16(afr[t][1], bfr[1][1], T1, 0, 0, 0);
            float4v hv4;
            if (bias) { hv4[0] = hv4[1] = hv4[2] = hv4[3] = 1.0f; }
            else {
#pragma unroll
                for (int rr = 0; rr < 4; rr++)
                    hv4[rr] = bf2f((unsigned short)(hu[t] >> (16 * rr)));
            }
            acc[t][0] += hv4 * T0;   // vector fma -> v_pk_fma_f32
            acc[t][1] += hv4 * T1;
        }
    }

    // ---- reduce 4 kg partials in 2 nf2-rounds (red overlays stage) ----
    int row_r = tid >> 3, cq = tid & 7;        // 64 rows x 8 col-chunks of 4
#pragma unroll
    for (int nf2 = 0; nf2 < 2; nf2++) {
        __syncthreads();   // red region free (round 0: also closes main loop)
#pragma unroll
        for (int t = 0; t < 4; t++)
#pragma unroll
            for (int rr = 0; rr < 4; rr++)
                red[kg * 2176 + (t * 16 + quad * 4 + rr) * 34 + nfh * 16 + l15] = acc[t][nf2][rr];
        __syncthreads();
        float4v s = {0.f, 0.f, 0.f, 0.f};
#pragma unroll
        for (int g2 = 0; g2 < 4; g2++) {
            const float* rp = red + g2 * 2176 + row_r * 34 + cq * 4;
#pragma unroll
            for (int j = 0; j < 4; j++) s[j] += rp[j];
        }
        int c34 = cq * 4;                       // 0..28
        int gcol = ((c34 >> 4) * 2 + nf2) * 16 + (c34 & 15);
        *(float4v*)(msgbuf + (size_t)(ebase + row_r) * 64 + gcol) = s;
    }
}

// ===================== fused node update ===================================
// Gathers msgbuf rows via dst-sorted edge list (no atomics, no agg buffer).
__global__ __launch_bounds__(256) void k_node(
    const unsigned short* __restrict__ hb_in,
    const unsigned short* __restrict__ rootTf,
    const unsigned short* __restrict__ wcombf,
    const float* __restrict__ msgbuf, const int* __restrict__ off,
    const int* __restrict__ eorder,
    const float* __restrict__ counts,
    const float* __restrict__ conv_b,
    const float* __restrict__ bih, const float* __restrict__ bhh,
    unsigned short* __restrict__ hb_out)
{
    __shared__ unsigned short m_lds[64 * 72];
    __shared__ float aggl[64 * 68];
    int tid = threadIdx.x, w = tid >> 6, lane = tid & 63;
    int l15 = lane & 15, quad = lane >> 4;
    int node0 = blockIdx.x * 64;
    int row0 = w * 16;

    // ---- gather-aggregate: 4 threads per node x 16 cols ----
    {
        int nl = tid >> 2, cg = tid & 3;
        int nn = node0 + nl;
        int s0 = off[nn], s1 = off[nn + 1];
        float acc[16] = {};
        for (int sl = s0; sl < s1; sl++) {
            int e = eorder[sl];
            const float* mr = msgbuf + (size_t)e * 64 + cg * 16;
#pragma unroll
            for (int q = 0; q < 4; q++) {
                float4v v = *(const float4v*)(mr + 4 * q);
#pragma unroll
                for (int j = 0; j < 4; j++) acc[4 * q + j] += v[j];
            }
        }
#pragma unroll
        for (int k = 0; k < 16; k++) aggl[nl * 68 + cg * 16 + k] = acc[k];
    }
    __syncthreads();

    float4v acc1[4] = {};
    {
        short8 a1[2];
#pragma unroll
        for (int kb = 0; kb < 2; kb++)
            a1[kb] = *(const short8*)(hb_in + (size_t)(node0 + row0 + l15) * 64 + kb * 32 + quad * 8);
#pragma unroll
        for (int kb = 0; kb < 2; kb++)
#pragma unroll
            for (int nf = 0; nf < 4; nf++) {
                short8 b = *(const short8*)(rootTf + (size_t)((kb * 4 + nf) * 64 + lane) * 8);
                acc1[nf] = __builtin_amdgcn_mfma_f32_16x16x32_bf16(a1[kb], b, acc1[nf], 0, 0, 0);
            }
    }
#pragma unroll
    for (int rr = 0; rr < 4; rr++) {
        int nl = row0 + quad * 4 + rr;
        float cnt = counts[node0 + nl]; if (cnt < 1.f) cnt = 1.f;
        float rcp = 1.f / cnt;
#pragma unroll
        for (int nf = 0; nf < 4; nf++) {
            int c = nf * 16 + l15;
            float av = aggl[nl * 68 + c];
            float mv = av * rcp + acc1[nf][rr] + conv_b[c];
            m_lds[nl * 72 + c] = f2bf(mv > 0.f ? mv : 0.f);
        }
    }
    __syncthreads();

    float4v acc2[16] = {};
#pragma unroll
    for (int kb = 0; kb < 4; kb++) {
        short8 a2;
        if (kb < 2)
            a2 = *(const short8*)(m_lds + (row0 + l15) * 72 + kb * 32 + quad * 8);
        else
            a2 = *(const short8*)(hb_in + (size_t)(node0 + row0 + l15) * 64 + (kb - 2) * 32 + quad * 8);
#pragma unroll
        for (int nf = 0; nf < 16; nf++) {
            short8 b = *(const short8*)(wcombf + (size_t)((kb * 16 + nf) * 64 + lane) * 8);
            acc2[nf] = __builtin_amdgcn_mfma_f32_16x16x32_bf16(a2, b, acc2[nf], 0, 0, 0);
        }
    }

#pragma unroll
    for (int nf0 = 0; nf0 < 4; nf0++) {
        int c = nf0 * 16 + l15;
        float br = bih[c] + bhh[c];
        float bz = bih[64 + c] + bhh[64 + c];
        float bni = bih[128 + c], bnh = bhh[128 + c];
#pragma unroll
        for (int rr = 0; rr < 4; rr++) {
            int node = node0 + row0 + quad * 4 + rr;
            float gr = 1.f / (1.f + __expf(-(acc2[nf0][rr] + br)));
            float gz = 1.f / (1.f + __expf(-(acc2[nf0 + 4][rr] + bz)));
            float ng = tanhf(acc2[nf0 + 8][rr] + bni + gr * (acc2[nf0 + 12][rr] + bnh));
            float ho = bf2f(hb_in[(size_t)node * 64 + c]);
            float hn = (1.f - gz) * ng + gz * ho;
            hb_out[(size_t)node * 64 + c] = f2bf(hn);
        }
    }
}

// ===================== MFMA decoder ========================================
__global__ __launch_bounds__(256) void k_decoder(
    const unsigned short* __restrict__ hb, const int* __restrict__ ei,
    const float* __restrict__ ea,
    const unsigned short* __restrict__ wd1f, const unsigned short* __restrict__ wd2f,
    const float* __restrict__ bd2,
    const float* __restrict__ Wd3, const float* __restrict__ bd3,
    float* __restrict__ out)
{
    __shared__ unsigned short d1f[4][1024];  // per-wave: 2 frags x 512
    __shared__ float d2s[4][16 * 33];        // per-wave: 16 edges x 32 (+pad)
    int tid = threadIdx.x, w = tid >> 6, lane = tid & 63;
    int l15 = lane & 15, quad = lane >> 4;
    int ebase = blockIdx.x * 64 + w * 16;
    int e = ebase + l15;
    int src = ei[e], dst = ei[N_EDGES + e];

    short8 a[5];
#pragma unroll
    for (int kb = 0; kb < 2; kb++) {
        a[kb]     = *(const short8*)(hb + (size_t)src * 64 + kb * 32 + quad * 8);
        a[2 + kb] = *(const short8*)(hb + (size_t)dst * 64 + kb * 32 + quad * 8);
    }
    {
        union { short8 v; unsigned short u[8]; } tea;
#pragma unroll
        for (int j = 0; j < 8; j++) {
            float vv = 0.f;
            if (quad == 0) vv = (j < 5) ? ea[(size_t)e * 5 + j] : (j == 5 ? 1.f : 0.f);
            tea.u[j] = f2bf(vv);
        }
        a[4] = tea.v;
    }

    float4v acc1[4] = {};
#pragma unroll
    for (int kb = 0; kb < 5; kb++)
#pragma unroll
        for (int nf = 0; nf < 4; nf++) {
            short8 b = *(const short8*)(wd1f + (size_t)((kb * 4 + nf) * 64 + lane) * 8);
            acc1[nf] = __builtin_amdgcn_mfma_f32_16x16x32_bf16(a[kb], b, acc1[nf], 0, 0, 0);
        }
#pragma unroll
    for (int nf = 0; nf < 4; nf++) {
        int kbp = nf >> 1;
        int lanep_hi = ((nf & 1) * 2 + (l15 >> 3)) * 16;
        int jp = l15 & 7;
#pragma unroll
        for (int r = 0; r < 4; r++) {
            float v = acc1[nf][r];
            d1f[w][kbp * 512 + (lanep_hi + quad * 4 + r) * 8 + jp] = f2bf(v > 0.f ? v : 0.f);
        }
    }
    float4v acc2[2] = {};
#pragma unroll
    for (int kb = 0; kb < 2; kb++) {
        short8 a2 = *(const short8*)(&d1f[w][kb * 512 + lane * 8]);
#pragma unroll
        for (int nf = 0; nf < 2; nf++) {
            short8 b = *(const short8*)(wd2f + (size_t)((kb * 2 + nf) * 64 + lane) * 8);
            acc2[nf] = __builtin_amdgcn_mfma_f32_16x16x32_bf16(a2, b, acc2[nf], 0, 0, 0);
        }
    }
#pragma unroll
    for (int nf = 0; nf < 2; nf++) {
        int c = nf * 16 + l15;
        float bias = bd2[c];
#pragma unroll
        for (int r = 0; r < 4; r++) {
            float v = acc2[nf][r] + bias;
            d2s[w][(quad * 4 + r) * 33 + c] = v > 0.f ? v : 0.f;
        }
    }
    {
        int e_l = lane >> 2, t = lane & 3;
        float s = bd3[t];
        const float* w3 = Wd3 + t * 32;
        const float* dr = &d2s[w][e_l * 33];
#pragma unroll
        for (int k = 0; k < 32; k++) s += w3[k] * dr[k];
        out[(size_t)(ebase + e_l) * 4 + t] = s;
    }
}

extern "C" void kernel_launch(void* const* d_in, const int* in_sizes, int n_in,
                              void* d_out, int out_size, void* d_ws, size_t ws_size,
                              hipStream_t stream)
{
    const float* x      = (const float*)d_in[0];
    const int*   ei     = (const int*)d_in[1];
    const float* ea     = (const float*)d_in[2];
    const float* u      = (const float*)d_in[3];
    const float* Wp     = (const float*)d_in[4];
    const float* bp     = (const float*)d_in[5];
    const float* We1    = (const float*)d_in[6];
    const float* be1    = (const float*)d_in[7];
    const float* We2    = (const float*)d_in[8];
    const float* be2    = (const float*)d_in[9];
    const float* root   = (const float*)d_in[10];
    const float* conv_b = (const float*)d_in[11];
    const float* Wih    = (const float*)d_in[12];
    const float* bih    = (const float*)d_in[13];
    const float* Whh    = (const float*)d_in[14];
    const float* bhh    = (const float*)d_in[15];
    const float* Wd1    = (const float*)d_in[16];
    const float* bd1    = (const float*)d_in[17];
    const float* Wd2    = (const float*)d_in[18];
    const float* bd2    = (const float*)d_in[19];
    const float* Wd3    = (const float*)d_in[20];
    const float* bd3    = (const float*)d_in[21];
    float* out = (float*)d_out;

    char* ws = (char*)d_ws;
    size_t off_b = 0;
    auto take = [&](size_t bytes) -> char* {
        char* p = ws + off_b; off_b = (off_b + bytes + 255) & ~(size_t)255; return p;
    };
    unsigned short* hb     = (unsigned short*)take((size_t)N_NODES * 64 * 2);
    unsigned short* hidT   = (unsigned short*)take((size_t)N_EDGES * 64 * 2);
    float*          msgbuf = (float*)take((size_t)N_EDGES * 64 * 4);
    float*          cnts   = (float*)take((size_t)N_NODES * 4);
    int*            off    = (int*)take((size_t)(N_NODES + 1) * 4);
    int*            eorder = (int*)take((size_t)N_EDGES * 4);
    unsigned short* w2tf   = (unsigned short*)take((size_t)66 * 4096 * 2);  // +1 pad blk
    unsigned short* rootTf = (unsigned short*)take((size_t)4096 * 2);
    unsigned short* wcombf = (unsigned short*)take((size_t)32768 * 2);
    unsigned short* wd1f   = (unsigned short*)take((size_t)10240 * 2);
    unsigned short* wd2f   = (unsigned short*)take((size_t)2048 * 2);
    (void)ws_size;

    k_setup<<<17616, 256, 0, stream>>>(root, Wih, Whh, We2, be2, Wd1, bd1, Wd2,
                                       x, u, Wp, bp, ea, We1, be1,
                                       rootTf, wcombf, w2tf, wd1f, wd2f,
                                       hb, hidT);
    k_graph<<<1, 1024, 0, stream>>>(ei, off, cnts, eorder);

    for (int s = 0; s < STEPS; s++) {
        k_msg_fused<<<N_EDGES / 64, 512, 0, stream>>>(hidT, hb, w2tf, ei, msgbuf);
        k_node<<<N_NODES / 64, 256, 0, stream>>>(hb, rootTf, wcombf, msgbuf, off,
                                                 eorder, cnts, conv_b, bih, bhh, hb);
    }
    k_decoder<<<N_EDGES / 64, 256, 0, stream>>>(hb, ei, ea, wd1f, wd2f, bd2,
                                                Wd3, bd3, out);
}

// Round 8
// 265.208 us; speedup vs baseline: 2.3052x; 1.1805x over previous
//
#include <hip/hip_runtime.h>
#include <hip/hip_bf16.h>
#include <stdint.h>

// MPNN latency predictor, MI355X — round 15.
// R14 post-mortem: k_graph (1-block CSR build) measured 80-92us — a single CU
// cannot hide 32 rounds of LDS-atomic latency; the 3-kernel build it replaced
// was ~8us. BUT the msg-at-16-waves/CU lever WORKED: 313-77 ~= 236 implies
// msg gained ~24us over R10 (confirming k_msg was latency/occupancy-bound;
// TLP was the lever, not stream BW, not barriers, not atomics).
// R15 = R14 msg/node/decoder + R10's measured-good CSR build (k_counts +
// k_scan + k_scatter, cnts-zero segment restored in k_setup).

#define N_NODES 32768
#define N_EDGES 32768
#define STEPS 3

typedef __attribute__((ext_vector_type(8))) short short8;   // 8 bf16 = 4 VGPRs
typedef __attribute__((ext_vector_type(4))) float float4v;  // MFMA C/D

__device__ __forceinline__ float bf2f(unsigned short u) {
    union { unsigned int i; float f; } v; v.i = ((unsigned int)u) << 16; return v.f;
}
__device__ __forceinline__ unsigned short f2bf(float f) {  // RNE
    union { float f; unsigned int i; } v; v.f = f;
    unsigned int x = v.i;
    return (unsigned short)((x + 0x7fffu + ((x >> 16) & 1u)) >> 16);
}

// async global->LDS, 16B/lane; lds dest = wave-uniform base + lane*16
__device__ __forceinline__ void gload_lds16(const void* g, void* l) {
    __builtin_amdgcn_global_load_lds(
        (__attribute__((address_space(1))) void*)g,
        (__attribute__((address_space(3))) void*)l, 16, 0, 0);
}

// ===================== fused setup kernel ==================================
// blockIdx segments:
//  [0,144)       rootTf (4096) + wcombf (32768)      — frag-interleaved
//  [144,1184)    w2tf (266240 valid + 4096 pad)       — frag-interleaved
//  [1184,1232)   wd1f (10240) + wd2f (2048)           — frag-interleaved
//  [1232,9424)   proj: hb = bf16(tanh([x,u]@Wp^T+bp))
//  [9424,17616)  edge hidden TRANSPOSED: hidT[j][e] = relu(ea@We1^T+be1)
//  [17616,17648) zero cnts (32768 floats)
__global__ __launch_bounds__(256) void k_setup(
    const float* __restrict__ root, const float* __restrict__ Wih,
    const float* __restrict__ Whh,
    const float* __restrict__ We2, const float* __restrict__ be2,
    const float* __restrict__ Wd1, const float* __restrict__ bd1,
    const float* __restrict__ Wd2,
    const float* __restrict__ x, const float* __restrict__ u,
    const float* __restrict__ Wp, const float* __restrict__ bp,
    const float* __restrict__ ea, const float* __restrict__ We1,
    const float* __restrict__ be1,
    unsigned short* __restrict__ rootTf, unsigned short* __restrict__ wcombf,
    unsigned short* __restrict__ w2tf,
    unsigned short* __restrict__ wd1f, unsigned short* __restrict__ wd2f,
    unsigned short* __restrict__ hb,
    unsigned short* __restrict__ hidT, float* __restrict__ cnts)
{
    int b = blockIdx.x, tid = threadIdx.x;
    if (b < 144) {
        int i = b * 256 + tid;
        if (i < 4096) {
            int j = i & 7, lane = (i >> 3) & 63, g = i >> 9;   // g<8
            int kb = g >> 2, nf = g & 3;
            int o = nf * 16 + (lane & 15);
            int k = kb * 32 + (lane >> 4) * 8 + j;
            rootTf[i] = f2bf(root[k * 64 + o]);
        } else if (i < 4096 + 32768) {
            int t = i - 4096;
            int j = t & 7, lane = (t >> 3) & 63, g = t >> 9;   // g<64
            int kb = g >> 4, nf = g & 15;
            int cp = nf * 16 + (lane & 15);
            int k = kb * 32 + (lane >> 4) * 8 + j;
            float v;
            if (cp < 128)      v = (k < 64) ? Wih[cp * 64 + k] : Whh[cp * 64 + (k - 64)];
            else if (cp < 192) v = (k < 64) ? Wih[cp * 64 + k] : 0.f;
            else               v = (k < 64) ? 0.f : Whh[(cp - 64) * 64 + (k - 64)];
            wcombf[t] = f2bf(v);
        }
    } else if (b < 1184) {
        int t = (b - 144) * 256 + tid;   // t < 266240
        if (t < 65 * 4096) {
            int kk = t >> 12, r = t & 4095;
            int j = r & 7, lane = (r >> 3) & 63, g = r >> 9;  // g<8
            int half = g >> 2, nf = g & 3;
            int o = nf * 16 + (lane & 15);
            int hh = half * 32 + (lane >> 4) * 8 + j;
            float v = (kk < 64) ? We2[((size_t)(hh * 64 + o)) * 64 + kk]
                                : be2[(size_t)hh * 64 + o];
            w2tf[t] = f2bf(v);
        }
    } else if (b < 1232) {
        int i = (b - 1184) * 256 + tid;
        if (i < 10240) {
            int j = i & 7, lane = (i >> 3) & 63, g = i >> 9;  // g<20
            int kb = g >> 2, nf = g & 3;
            int o = nf * 16 + (lane & 15);
            int k = kb * 32 + (lane >> 4) * 8 + j;
            float v = (k < 133) ? Wd1[(size_t)o * 133 + k] : (k == 133 ? bd1[o] : 0.f);
            wd1f[i] = f2bf(v);
        } else if (i < 10240 + 2048) {
            int t = i - 10240;
            int j = t & 7, lane = (t >> 3) & 63, g = t >> 9;  // g<4
            int kb = g >> 1, nf = g & 1;
            int o = nf * 16 + (lane & 15);
            int k = kb * 32 + (lane >> 4) * 8 + j;
            wd2f[t] = f2bf(Wd2[(size_t)o * 64 + k]);
        }
    } else if (b < 9424) {
        int idx = (b - 1232) * 256 + tid;
        int n = idx >> 6, j = idx & 63;
        const float* wr = Wp + j * 23;
        const float* xr = x + (size_t)n * 12;
        float s = bp[j];
#pragma unroll
        for (int i = 0; i < 12; i++) s += xr[i] * wr[i];
#pragma unroll
        for (int i = 0; i < 11; i++) s += u[i] * wr[12 + i];
        hb[idx] = f2bf(tanhf(s));
    } else if (b < 17616) {
        int idx = (b - 9424) * 256 + tid;           // idx < 2^21
        int el = idx & 63, j = (idx >> 6) & 63, eb = idx >> 12;
        int e = eb * 64 + el;                       // lane-varying e -> coalesced
        float s = be1[j];
#pragma unroll
        for (int i = 0; i < 5; i++) s += ea[(size_t)e * 5 + i] * We1[j * 5 + i];
        hidT[(size_t)j * N_EDGES + e] = f2bf(s > 0.f ? s : 0.f);
    } else {
        int idx = (b - 17616) * 1024 + tid * 4;
        if (idx < 32768) {
            float4v z = {0.f, 0.f, 0.f, 0.f};
            *(float4v*)(cnts + idx) = z;
        }
    }
}

__global__ __launch_bounds__(256) void k_counts(
    const int* __restrict__ ei, float* __restrict__ counts)
{
    int i = blockIdx.x * 256 + threadIdx.x;
    if (i < N_EDGES) atomicAdd(&counts[ei[N_EDGES + i]], 1.0f);
}

// one-time exclusive prefix sum of counts -> off[0..N], plus working copy woff
__global__ __launch_bounds__(1024) void k_scan(
    const float* __restrict__ cnts, int* __restrict__ off, int* __restrict__ woff)
{
    __shared__ int part[1024];
    int t = threadIdx.x;
    int loc[32];
    int s = 0;
#pragma unroll
    for (int i = 0; i < 32; i++) { loc[i] = s; s += (int)cnts[t * 32 + i]; }
    part[t] = s;
    __syncthreads();
    for (int d = 1; d < 1024; d <<= 1) {
        int y = (t >= d) ? part[t - d] : 0;
        __syncthreads();
        part[t] += y;
        __syncthreads();
    }
    int pre = (t == 0) ? 0 : part[t - 1];
#pragma unroll
    for (int i = 0; i < 32; i++) {
        off[t * 32 + i] = pre + loc[i];
        woff[t * 32 + i] = pre + loc[i];
    }
    if (t == 1023) off[32768] = part[1023];
}

// one-time: place edge ids into dst-sorted slots (32K atomics, once)
__global__ __launch_bounds__(256) void k_scatter(
    const int* __restrict__ ei, int* __restrict__ woff, int* __restrict__ eorder)
{
    int e = blockIdx.x * 256 + threadIdx.x;
    if (e < N_EDGES) {
        int d = ei[N_EDGES + e];
        int slot = atomicAdd(&woff[d], 1);
        eorder[slot] = e;
    }
}

// ===================== fused msg GEMM ======================================
// 512 blocks x 512 threads = 8 waves: wave = nfh*4 + kg. 64 edges/block.
// kg in {0..3}: kk-slice kg*16..+15 (kg=3 also kk=64 bias row).
// nfh in {0,1}: output col-half. Wave-private staged slice (4KB/kk),
// double-buffered, counted vmcnt(4), ZERO loop barriers.
// LDS 72KB -> 2 blocks/CU -> 16 waves/CU (msg is latency-bound; TLP is the
// proven lever, R14: ~24us gain). hv strip SHARED across nfh (one prologue
// barrier). Epilogue: 2 nf2-rounds LDS reduce over 4 kg partials.
__global__ __launch_bounds__(512, 4) void k_msg_fused(
    const unsigned short* __restrict__ hidT,  // (64, E) bf16
    const unsigned short* __restrict__ hb,    // (N,64) bf16
    const unsigned short* __restrict__ w2tf,  // (66*4096) frag-interleaved
    const int* __restrict__ ei,
    float* __restrict__ msgbuf)               // (E,64) f32 dense
{
    // LDS: [0,65536)      stage: 8 waves x 2 db x 2048 ushort (4KB slices)
    //      [65536,73728)  hvl: 64 kk x 64 e bf16 (shared)
    //      reduce overlay on stage: red[4 kg][64 row][34] f32 = 34816B
    __shared__ __attribute__((aligned(16))) unsigned char smem[73728];
    unsigned short* stg = (unsigned short*)smem;
    unsigned short* hvl = (unsigned short*)(smem + 65536);
    float* red = (float*)smem;

    int tid = threadIdx.x, w = tid >> 6, lane = tid & 63;
    int l15 = lane & 15, quad = lane >> 4;
    int kg = w & 3, nfh = w >> 2;
    int ebase = blockIdx.x * 64;
    int n_w = 16 + (kg == 3 ? 1 : 0);   // kg3 takes the bias row kk=64

    // ---- hv strip (shared): wave w loads rows w*8..w*8+7 ----
#pragma unroll
    for (int i = 0; i < 8; i++) {
        int row = w * 8 + i;
        hvl[row * 64 + lane] = hidT[(size_t)row * N_EDGES + ebase + lane];
    }
    __syncthreads();   // hv visible to all waves (one-time; drains vm+lgkm)

    // ---- static A-frags: 4 edge-tiles x 2 K-halves of h[src] (bf16) ----
    short8 afr[4][2];
#pragma unroll
    for (int t = 0; t < 4; t++) {
        int src = ei[ebase + t * 16 + l15];
#pragma unroll
        for (int hh = 0; hh < 2; hh++)
            afr[t][hh] = *(const short8*)(hb + (size_t)src * 64 + hh * 32 + quad * 8);
    }

    unsigned short* wbuf = stg + w * 4096;   // 2 db x 2048
    // stage kk-row (kg*16+r)'s 4 frag-groups for my nf-half into wbuf[db]
    auto stage = [&](int r, int db) {
        const unsigned short* g = w2tf + (size_t)(kg * 16 + r) * 4096;
        unsigned short* d = wbuf + db * 2048;
#pragma unroll
        for (int c = 0; c < 4; c++) {             // c = hh*2 + j (j = nf2)
            int hh = c >> 1, j = c & 1;
            gload_lds16(g + (hh * 4 + nfh * 2 + j) * 512 + lane * 8, d + c * 512);
        }
    };

    stage(0, 0);
    stage(1, 1);

    float4v acc[4][2] = {};   // [tile][nf2]
    for (int r = 0; r < n_w; r++) {
        int db = r & 1;
        // stage r complete; stage r+1's 4 loads may remain in flight
        if (r < n_w - 1) { asm volatile("s_waitcnt vmcnt(4)" ::: "memory"); }
        else             { asm volatile("s_waitcnt vmcnt(0)" ::: "memory"); }

        bool bias = (r == 16);
        short8 bfr[2][2];
        const unsigned short* bb = wbuf + db * 2048;
#pragma unroll
        for (int hh = 0; hh < 2; hh++)
#pragma unroll
            for (int j = 0; j < 2; j++)
                bfr[hh][j] = *(const short8*)(bb + (hh * 2 + j) * 512 + lane * 8);

        unsigned long long hu[4] = {};
        if (!bias) {
#pragma unroll
            for (int t = 0; t < 4; t++)
                hu[t] = *(const unsigned long long*)(hvl + (kg * 16 + r) * 64 + t * 16 + quad * 4);
        }

        asm volatile("s_waitcnt lgkmcnt(0)" ::: "memory");  // my LDS reads done
        if (r + 2 < n_w) stage(r + 2, db);

#pragma unroll
        for (int t = 0; t < 4; t++) {
            float4v z = {0.f, 0.f, 0.f, 0.f};
            float4v T0 = __builtin_amdgcn_mfma_f32_16x16x32_bf16(afr[t][0], bfr[0][0], z, 0, 0, 0);
            T0 = __builtin_amdgcn_mfma_f32_16x16x32_bf16(afr[t][1], bfr[1][0], T0, 0, 0, 0);
            float4v T1 = __builtin_amdgcn_mfma_f32_16x16x32_bf16(afr[t][0], bfr[0][1], z, 0, 0, 0);
            T1 = __builtin_amdgcn_mfma_f32_16x16x32_bf16(afr[t][1], bfr[1][1], T1, 0, 0, 0);
            float4v hv4;
            if (bias) { hv4[0] = hv4[1] = hv4[2] = hv4[3] = 1.0f; }
            else {
#pragma unroll
                for (int rr = 0; rr < 4; rr++)
                    hv4[rr] = bf2f((unsigned short)(hu[t] >> (16 * rr)));
            }
            acc[t][0] += hv4 * T0;   // vector fma -> v_pk_fma_f32
            acc[t][1] += hv4 * T1;
        }
    }

    // ---- reduce 4 kg partials in 2 nf2-rounds (red overlays stage) ----
    int row_r = tid >> 3, cq = tid & 7;        // 64 rows x 8 col-chunks of 4
#pragma unroll
    for (int nf2 = 0; nf2 < 2; nf2++) {
        __syncthreads();   // red region free (round 0: also closes main loop)
#pragma unroll
        for (int t = 0; t < 4; t++)
#pragma unroll
            for (int rr = 0; rr < 4; rr++)
                red[kg * 2176 + (t * 16 + quad * 4 + rr) * 34 + nfh * 16 + l15] = acc[t][nf2][rr];
        __syncthreads();
        float4v s = {0.f, 0.f, 0.f, 0.f};
#pragma unroll
        for (int g2 = 0; g2 < 4; g2++) {
            const float* rp = red + g2 * 2176 + row_r * 34 + cq * 4;
#pragma unroll
            for (int j = 0; j < 4; j++) s[j] += rp[j];
        }
        int c34 = cq * 4;                       // 0..28
        int gcol = ((c34 >> 4) * 2 + nf2) * 16 + (c34 & 15);
        *(float4v*)(msgbuf + (size_t)(ebase + row_r) * 64 + gcol) = s;
    }
}

// ===================== fused node update ===================================
// Gathers msgbuf rows via dst-sorted edge list (no atomics, no agg buffer).
__global__ __launch_bounds__(256) void k_node(
    const unsigned short* __restrict__ hb_in,
    const unsigned short* __restrict__ rootTf,
    const unsigned short* __restrict__ wcombf,
    const float* __restrict__ msgbuf, const int* __restrict__ off,
    const int* __restrict__ eorder,
    const float* __restrict__ counts,
    const float* __restrict__ conv_b,
    const float* __restrict__ bih, const float* __restrict__ bhh,
    unsigned short* __restrict__ hb_out)
{
    __shared__ unsigned short m_lds[64 * 72];
    __shared__ float aggl[64 * 68];
    int tid = threadIdx.x, w = tid >> 6, lane = tid & 63;
    int l15 = lane & 15, quad = lane >> 4;
    int node0 = blockIdx.x * 64;
    int row0 = w * 16;

    // ---- gather-aggregate: 4 threads per node x 16 cols ----
    {
        int nl = tid >> 2, cg = tid & 3;
        int nn = node0 + nl;
        int s0 = off[nn], s1 = off[nn + 1];
        float acc[16] = {};
        for (int sl = s0; sl < s1; sl++) {
            int e = eorder[sl];
            const float* mr = msgbuf + (size_t)e * 64 + cg * 16;
#pragma unroll
            for (int q = 0; q < 4; q++) {
                float4v v = *(const float4v*)(mr + 4 * q);
#pragma unroll
                for (int j = 0; j < 4; j++) acc[4 * q + j] += v[j];
            }
        }
#pragma unroll
        for (int k = 0; k < 16; k++) aggl[nl * 68 + cg * 16 + k] = acc[k];
    }
    __syncthreads();

    float4v acc1[4] = {};
    {
        short8 a1[2];
#pragma unroll
        for (int kb = 0; kb < 2; kb++)
            a1[kb] = *(const short8*)(hb_in + (size_t)(node0 + row0 + l15) * 64 + kb * 32 + quad * 8);
#pragma unroll
        for (int kb = 0; kb < 2; kb++)
#pragma unroll
            for (int nf = 0; nf < 4; nf++) {
                short8 b = *(const short8*)(rootTf + (size_t)((kb * 4 + nf) * 64 + lane) * 8);
                acc1[nf] = __builtin_amdgcn_mfma_f32_16x16x32_bf16(a1[kb], b, acc1[nf], 0, 0, 0);
            }
    }
#pragma unroll
    for (int rr = 0; rr < 4; rr++) {
        int nl = row0 + quad * 4 + rr;
        float cnt = counts[node0 + nl]; if (cnt < 1.f) cnt = 1.f;
        float rcp = 1.f / cnt;
#pragma unroll
        for (int nf = 0; nf < 4; nf++) {
            int c = nf * 16 + l15;
            float av = aggl[nl * 68 + c];
            float mv = av * rcp + acc1[nf][rr] + conv_b[c];
            m_lds[nl * 72 + c] = f2bf(mv > 0.f ? mv : 0.f);
        }
    }
    __syncthreads();

    float4v acc2[16] = {};
#pragma unroll
    for (int kb = 0; kb < 4; kb++) {
        short8 a2;
        if (kb < 2)
            a2 = *(const short8*)(m_lds + (row0 + l15) * 72 + kb * 32 + quad * 8);
        else
            a2 = *(const short8*)(hb_in + (size_t)(node0 + row0 + l15) * 64 + (kb - 2) * 32 + quad * 8);
#pragma unroll
        for (int nf = 0; nf < 16; nf++) {
            short8 b = *(const short8*)(wcombf + (size_t)((kb * 16 + nf) * 64 + lane) * 8);
            acc2[nf] = __builtin_amdgcn_mfma_f32_16x16x32_bf16(a2, b, acc2[nf], 0, 0, 0);
        }
    }

#pragma unroll
    for (int nf0 = 0; nf0 < 4; nf0++) {
        int c = nf0 * 16 + l15;
        float br = bih[c] + bhh[c];
        float bz = bih[64 + c] + bhh[64 + c];
        float bni = bih[128 + c], bnh = bhh[128 + c];
#pragma unroll
        for (int rr = 0; rr < 4; rr++) {
            int node = node0 + row0 + quad * 4 + rr;
            float gr = 1.f / (1.f + __expf(-(acc2[nf0][rr] + br)));
            float gz = 1.f / (1.f + __expf(-(acc2[nf0 + 4][rr] + bz)));
            float ng = tanhf(acc2[nf0 + 8][rr] + bni + gr * (acc2[nf0 + 12][rr] + bnh));
            float ho = bf2f(hb_in[(size_t)node * 64 + c]);
            float hn = (1.f - gz) * ng + gz * ho;
            hb_out[(size_t)node * 64 + c] = f2bf(hn);
        }
    }
}

// ===================== MFMA decoder ========================================
__global__ __launch_bounds__(256) void k_decoder(
    const unsigned short* __restrict__ hb, const int* __restrict__ ei,
    const float* __restrict__ ea,
    const unsigned short* __restrict__ wd1f, const unsigned short* __restrict__ wd2f,
    const float* __restrict__ bd2,
    const float* __restrict__ Wd3, const float* __restrict__ bd3,
    float* __restrict__ out)
{
    __shared__ unsigned short d1f[4][1024];  // per-wave: 2 frags x 512
    __shared__ float d2s[4][16 * 33];        // per-wave: 16 edges x 32 (+pad)
    int tid = threadIdx.x, w = tid >> 6, lane = tid & 63;
    int l15 = lane & 15, quad = lane >> 4;
    int ebase = blockIdx.x * 64 + w * 16;
    int e = ebase + l15;
    int src = ei[e], dst = ei[N_EDGES + e];

    short8 a[5];
#pragma unroll
    for (int kb = 0; kb < 2; kb++) {
        a[kb]     = *(const short8*)(hb + (size_t)src * 64 + kb * 32 + quad * 8);
        a[2 + kb] = *(const short8*)(hb + (size_t)dst * 64 + kb * 32 + quad * 8);
    }
    {
        union { short8 v; unsigned short u[8]; } tea;
#pragma unroll
        for (int j = 0; j < 8; j++) {
            float vv = 0.f;
            if (quad == 0) vv = (j < 5) ? ea[(size_t)e * 5 + j] : (j == 5 ? 1.f : 0.f);
            tea.u[j] = f2bf(vv);
        }
        a[4] = tea.v;
    }

    float4v acc1[4] = {};
#pragma unroll
    for (int kb = 0; kb < 5; kb++)
#pragma unroll
        for (int nf = 0; nf < 4; nf++) {
            short8 b = *(const short8*)(wd1f + (size_t)((kb * 4 + nf) * 64 + lane) * 8);
            acc1[nf] = __builtin_amdgcn_mfma_f32_16x16x32_bf16(a[kb], b, acc1[nf], 0, 0, 0);
        }
#pragma unroll
    for (int nf = 0; nf < 4; nf++) {
        int kbp = nf >> 1;
        int lanep_hi = ((nf & 1) * 2 + (l15 >> 3)) * 16;
        int jp = l15 & 7;
#pragma unroll
        for (int r = 0; r < 4; r++) {
            float v = acc1[nf][r];
            d1f[w][kbp * 512 + (lanep_hi + quad * 4 + r) * 8 + jp] = f2bf(v > 0.f ? v : 0.f);
        }
    }
    float4v acc2[2] = {};
#pragma unroll
    for (int kb = 0; kb < 2; kb++) {
        short8 a2 = *(const short8*)(&d1f[w][kb * 512 + lane * 8]);
#pragma unroll
        for (int nf = 0; nf < 2; nf++) {
            short8 b = *(const short8*)(wd2f + (size_t)((kb * 2 + nf) * 64 + lane) * 8);
            acc2[nf] = __builtin_amdgcn_mfma_f32_16x16x32_bf16(a2, b, acc2[nf], 0, 0, 0);
        }
    }
#pragma unroll
    for (int nf = 0; nf < 2; nf++) {
        int c = nf * 16 + l15;
        float bias = bd2[c];
#pragma unroll
        for (int r = 0; r < 4; r++) {
            float v = acc2[nf][r] + bias;
            d2s[w][(quad * 4 + r) * 33 + c] = v > 0.f ? v : 0.f;
        }
    }
    {
        int e_l = lane >> 2, t = lane & 3;
        float s = bd3[t];
        const float* w3 = Wd3 + t * 32;
        const float* dr = &d2s[w][e_l * 33];
#pragma unroll
        for (int k = 0; k < 32; k++) s += w3[k] * dr[k];
        out[(size_t)(ebase + e_l) * 4 + t] = s;
    }
}

extern "C" void kernel_launch(void* const* d_in, const int* in_sizes, int n_in,
                              void* d_out, int out_size, void* d_ws, size_t ws_size,
                              hipStream_t stream)
{
    const float* x      = (const float*)d_in[0];
    const int*   ei     = (const int*)d_in[1];
    const float* ea     = (const float*)d_in[2];
    const float* u      = (const float*)d_in[3];
    const float* Wp     = (const float*)d_in[4];
    const float* bp     = (const float*)d_in[5];
    const float* We1    = (const float*)d_in[6];
    const float* be1    = (const float*)d_in[7];
    const float* We2    = (const float*)d_in[8];
    const float* be2    = (const float*)d_in[9];
    const float* root   = (const float*)d_in[10];
    const float* conv_b = (const float*)d_in[11];
    const float* Wih    = (const float*)d_in[12];
    const float* bih    = (const float*)d_in[13];
    const float* Whh    = (const float*)d_in[14];
    const float* bhh    = (const float*)d_in[15];
    const float* Wd1    = (const float*)d_in[16];
    const float* bd1    = (const float*)d_in[17];
    const float* Wd2    = (const float*)d_in[18];
    const float* bd2    = (const float*)d_in[19];
    const float* Wd3    = (const float*)d_in[20];
    const float* bd3    = (const float*)d_in[21];
    float* out = (float*)d_out;

    char* ws = (char*)d_ws;
    size_t off_b = 0;
    auto take = [&](size_t bytes) -> char* {
        char* p = ws + off_b; off_b = (off_b + bytes + 255) & ~(size_t)255; return p;
    };
    unsigned short* hb     = (unsigned short*)take((size_t)N_NODES * 64 * 2);
    unsigned short* hidT   = (unsigned short*)take((size_t)N_EDGES * 64 * 2);
    float*          msgbuf = (float*)take((size_t)N_EDGES * 64 * 4);
    float*          cnts   = (float*)take((size_t)N_NODES * 4);
    int*            off    = (int*)take((size_t)(N_NODES + 1) * 4);
    int*            woff   = (int*)take((size_t)N_NODES * 4);
    int*            eorder = (int*)take((size_t)N_EDGES * 4);
    unsigned short* w2tf   = (unsigned short*)take((size_t)66 * 4096 * 2);  // +1 pad blk
    unsigned short* rootTf = (unsigned short*)take((size_t)4096 * 2);
    unsigned short* wcombf = (unsigned short*)take((size_t)32768 * 2);
    unsigned short* wd1f   = (unsigned short*)take((size_t)10240 * 2);
    unsigned short* wd2f   = (unsigned short*)take((size_t)2048 * 2);
    (void)ws_size;

    k_setup<<<17648, 256, 0, stream>>>(root, Wih, Whh, We2, be2, Wd1, bd1, Wd2,
                                       x, u, Wp, bp, ea, We1, be1,
                                       rootTf, wcombf, w2tf, wd1f, wd2f,
                                       hb, hidT, cnts);
    k_counts<<<128, 256, 0, stream>>>(ei, cnts);
    k_scan<<<1, 1024, 0, stream>>>(cnts, off, woff);
    k_scatter<<<128, 256, 0, stream>>>(ei, woff, eorder);

    for (int s = 0; s < STEPS; s++) {
        k_msg_fused<<<N_EDGES / 64, 512, 0, stream>>>(hidT, hb, w2tf, ei, msgbuf);
        k_node<<<N_NODES / 64, 256, 0, stream>>>(hb, rootTf, wcombf, msgbuf, off,
                                                 eorder, cnts, conv_b, bih, bhh, hb);
    }
    k_decoder<<<N_EDGES / 64, 256, 0, stream>>>(hb, ei, ea, wd1f, wd2f, bd2,
                                                Wd3, bd3, out);
}

// Round 9
// 264.772 us; speedup vs baseline: 2.3090x; 1.0016x over previous
//
#include <hip/hip_runtime.h>
#include <hip/hip_bf16.h>
#include <stdint.h>

// MPNN latency predictor, MI355X — round 16.
// R15 A/B verdict: msg at 16 waves/CU (R14/R15) is neutral-to-negative vs
// R10's 8 waves/CU (259.7 vs 265.2) — extra TLP cancelled by doubled per-CU
// w2tf stream pressure. R14's inferred "+24us msg gain" was cross-session
// arithmetic noise. Session ledger: atomics-removal ~0, stream-halving ~0,
// barrier variants negative, persistence catastrophic (fence = L2 flush),
// occupancy doubling ~0. Best measured config = R10 (259.7us). R16 restores
// it verbatim. Timed region = ~168us harness poison fills (80% HBM peak,
// fixed) + ~92us our kernels (all major hypotheses falsified within noise).

#define N_NODES 32768
#define N_EDGES 32768
#define STEPS 3

typedef __attribute__((ext_vector_type(8))) short short8;   // 8 bf16 = 4 VGPRs
typedef __attribute__((ext_vector_type(4))) float float4v;  // MFMA C/D

__device__ __forceinline__ float bf2f(unsigned short u) {
    union { unsigned int i; float f; } v; v.i = ((unsigned int)u) << 16; return v.f;
}
__device__ __forceinline__ unsigned short f2bf(float f) {  // RNE
    union { float f; unsigned int i; } v; v.f = f;
    unsigned int x = v.i;
    return (unsigned short)((x + 0x7fffu + ((x >> 16) & 1u)) >> 16);
}

// async global->LDS, 16B/lane; lds dest = wave-uniform base + lane*16
__device__ __forceinline__ void gload_lds16(const void* g, void* l) {
    __builtin_amdgcn_global_load_lds(
        (__attribute__((address_space(1))) void*)g,
        (__attribute__((address_space(3))) void*)l, 16, 0, 0);
}

// ===================== fused setup kernel ==================================
// blockIdx segments:
//  [0,144)       rootTf (4096) + wcombf (32768)      — frag-interleaved
//  [144,1184)    w2tf (266240 valid + 4096 pad)       — frag-interleaved
//  [1184,1232)   wd1f (10240) + wd2f (2048)           — frag-interleaved
//  [1232,9424)   proj: hb = bf16(tanh([x,u]@Wp^T+bp))
//  [9424,17616)  edge hidden TRANSPOSED: hidT[j][e] = relu(ea@We1^T+be1)
//  [17616,17648) zero cnts (32768 floats)
__global__ __launch_bounds__(256) void k_setup(
    const float* __restrict__ root, const float* __restrict__ Wih,
    const float* __restrict__ Whh,
    const float* __restrict__ We2, const float* __restrict__ be2,
    const float* __restrict__ Wd1, const float* __restrict__ bd1,
    const float* __restrict__ Wd2,
    const float* __restrict__ x, const float* __restrict__ u,
    const float* __restrict__ Wp, const float* __restrict__ bp,
    const float* __restrict__ ea, const float* __restrict__ We1,
    const float* __restrict__ be1,
    unsigned short* __restrict__ rootTf, unsigned short* __restrict__ wcombf,
    unsigned short* __restrict__ w2tf,
    unsigned short* __restrict__ wd1f, unsigned short* __restrict__ wd2f,
    unsigned short* __restrict__ hb,
    unsigned short* __restrict__ hidT, float* __restrict__ cnts)
{
    int b = blockIdx.x, tid = threadIdx.x;
    if (b < 144) {
        int i = b * 256 + tid;
        if (i < 4096) {
            int j = i & 7, lane = (i >> 3) & 63, g = i >> 9;   // g<8
            int kb = g >> 2, nf = g & 3;
            int o = nf * 16 + (lane & 15);
            int k = kb * 32 + (lane >> 4) * 8 + j;
            rootTf[i] = f2bf(root[k * 64 + o]);
        } else if (i < 4096 + 32768) {
            int t = i - 4096;
            int j = t & 7, lane = (t >> 3) & 63, g = t >> 9;   // g<64
            int kb = g >> 4, nf = g & 15;
            int cp = nf * 16 + (lane & 15);
            int k = kb * 32 + (lane >> 4) * 8 + j;
            float v;
            if (cp < 128)      v = (k < 64) ? Wih[cp * 64 + k] : Whh[cp * 64 + (k - 64)];
            else if (cp < 192) v = (k < 64) ? Wih[cp * 64 + k] : 0.f;
            else               v = (k < 64) ? 0.f : Whh[(cp - 64) * 64 + (k - 64)];
            wcombf[t] = f2bf(v);
        }
    } else if (b < 1184) {
        int t = (b - 144) * 256 + tid;   // t < 266240
        if (t < 65 * 4096) {
            int kk = t >> 12, r = t & 4095;
            int j = r & 7, lane = (r >> 3) & 63, g = r >> 9;  // g<8
            int half = g >> 2, nf = g & 3;
            int o = nf * 16 + (lane & 15);
            int hh = half * 32 + (lane >> 4) * 8 + j;
            float v = (kk < 64) ? We2[((size_t)(hh * 64 + o)) * 64 + kk]
                                : be2[(size_t)hh * 64 + o];
            w2tf[t] = f2bf(v);
        }
    } else if (b < 1232) {
        int i = (b - 1184) * 256 + tid;
        if (i < 10240) {
            int j = i & 7, lane = (i >> 3) & 63, g = i >> 9;  // g<20
            int kb = g >> 2, nf = g & 3;
            int o = nf * 16 + (lane & 15);
            int k = kb * 32 + (lane >> 4) * 8 + j;
            float v = (k < 133) ? Wd1[(size_t)o * 133 + k] : (k == 133 ? bd1[o] : 0.f);
            wd1f[i] = f2bf(v);
        } else if (i < 10240 + 2048) {
            int t = i - 10240;
            int j = t & 7, lane = (t >> 3) & 63, g = t >> 9;  // g<4
            int kb = g >> 1, nf = g & 1;
            int o = nf * 16 + (lane & 15);
            int k = kb * 32 + (lane >> 4) * 8 + j;
            wd2f[t] = f2bf(Wd2[(size_t)o * 64 + k]);
        }
    } else if (b < 9424) {
        int idx = (b - 1232) * 256 + tid;
        int n = idx >> 6, j = idx & 63;
        const float* wr = Wp + j * 23;
        const float* xr = x + (size_t)n * 12;
        float s = bp[j];
#pragma unroll
        for (int i = 0; i < 12; i++) s += xr[i] * wr[i];
#pragma unroll
        for (int i = 0; i < 11; i++) s += u[i] * wr[12 + i];
        hb[idx] = f2bf(tanhf(s));
    } else if (b < 17616) {
        int idx = (b - 9424) * 256 + tid;           // idx < 2^21
        int el = idx & 63, j = (idx >> 6) & 63, eb = idx >> 12;
        int e = eb * 64 + el;                       // lane-varying e -> coalesced
        float s = be1[j];
#pragma unroll
        for (int i = 0; i < 5; i++) s += ea[(size_t)e * 5 + i] * We1[j * 5 + i];
        hidT[(size_t)j * N_EDGES + e] = f2bf(s > 0.f ? s : 0.f);
    } else {
        int idx = (b - 17616) * 1024 + tid * 4;
        if (idx < 32768) {
            float4v z = {0.f, 0.f, 0.f, 0.f};
            *(float4v*)(cnts + idx) = z;
        }
    }
}

__global__ __launch_bounds__(256) void k_counts(
    const int* __restrict__ ei, float* __restrict__ counts)
{
    int i = blockIdx.x * 256 + threadIdx.x;
    if (i < N_EDGES) atomicAdd(&counts[ei[N_EDGES + i]], 1.0f);
}

// one-time exclusive prefix sum of counts -> off[0..N], plus working copy woff
__global__ __launch_bounds__(1024) void k_scan(
    const float* __restrict__ cnts, int* __restrict__ off, int* __restrict__ woff)
{
    __shared__ int part[1024];
    int t = threadIdx.x;
    int loc[32];
    int s = 0;
#pragma unroll
    for (int i = 0; i < 32; i++) { loc[i] = s; s += (int)cnts[t * 32 + i]; }
    part[t] = s;
    __syncthreads();
    for (int d = 1; d < 1024; d <<= 1) {
        int y = (t >= d) ? part[t - d] : 0;
        __syncthreads();
        part[t] += y;
        __syncthreads();
    }
    int pre = (t == 0) ? 0 : part[t - 1];
#pragma unroll
    for (int i = 0; i < 32; i++) {
        off[t * 32 + i] = pre + loc[i];
        woff[t * 32 + i] = pre + loc[i];
    }
    if (t == 1023) off[32768] = part[1023];
}

// one-time: place edge ids into dst-sorted slots (32K atomics, once)
__global__ __launch_bounds__(256) void k_scatter(
    const int* __restrict__ ei, int* __restrict__ woff, int* __restrict__ eorder)
{
    int e = blockIdx.x * 256 + threadIdx.x;
    if (e < N_EDGES) {
        int d = ei[N_EDGES + e];
        int slot = atomicAdd(&woff[d], 1);
        eorder[slot] = e;
    }
}

// ===================== fused msg GEMM ======================================
// 512 blocks x 256 threads = 4 waves, 64 edges/block, 2 blocks/CU (72KB LDS).
// Wave w owns kk-slice w*16..w*16+15 (wave 3 also kk=64 = bias row, hv=1).
// Per kk: T[tile] = Hsrc(16x64) @ W2[kk](64x64) via 8 MFMA with STATIC bf16
// A-frags; acc += hid[e,kk] * T (v_fmac). B-frags reused across 4 M-tiles.
// Wave-private dbuf staging, counted vmcnt, no barriers until the reduce.
// Epilogue: cross-wave LDS reduce, then PLAIN coalesced stores to msgbuf.
__global__ __launch_bounds__(256, 2) void k_msg_fused(
    const unsigned short* __restrict__ hidT,  // (64, E) bf16
    const unsigned short* __restrict__ hb,    // (N,64) bf16
    const unsigned short* __restrict__ w2tf,  // (66*4096) frag-interleaved
    const int* __restrict__ ei,
    float* __restrict__ msgbuf)               // (E,64) f32 dense
{
    // LDS map: [0,65536) staging 4 waves x 2 dbuf x 8192B
    //          [65536,73728) hv strip: 4 waves x 16 r x 64 e bf16
    //          reduce overlay (after loop): [0,67584) 4 x 64 x 66 f32
    __shared__ __attribute__((aligned(16))) unsigned char smem[73728];
    unsigned short* stg = (unsigned short*)smem;
    unsigned short* hvl = (unsigned short*)(smem + 65536);
    float* red = (float*)smem;

    int tid = threadIdx.x, w = tid >> 6, lane = tid & 63;
    int l15 = lane & 15, quad = lane >> 4;
    int ebase = blockIdx.x * 64;
    int n = 16 + (w == 3 ? 1 : 0);   // wave 3 takes the bias row kk=64

    // ---- preamble: hv rows (coalesced 128B each) -> per-wave LDS strip ----
    {
        const unsigned short* hp = hidT + (size_t)(w * 16) * N_EDGES + ebase + lane;
        unsigned short* dp = hvl + (w * 16) * 64 + lane;
#pragma unroll
        for (int r = 0; r < 16; r++)
            dp[r * 64] = hp[(size_t)r * N_EDGES];
    }
    // ---- static A-frags: 4 edge-tiles x 2 K-halves of h[src] (bf16) ----
    short8 afr[4][2];
#pragma unroll
    for (int t = 0; t < 4; t++) {
        int src = ei[ebase + t * 16 + l15];
#pragma unroll
        for (int hh = 0; hh < 2; hh++)
            afr[t][hh] = *(const short8*)(hb + (size_t)src * 64 + hh * 32 + quad * 8);
    }

    unsigned short* wbuf = stg + w * (2 * 4096);
    auto stage = [&](int r, int db) {
        const unsigned short* g = w2tf + (size_t)(w * 16 + r) * 4096;
        unsigned short* d = wbuf + db * 4096;
#pragma unroll
        for (int c = 0; c < 8; c++)
            gload_lds16(g + (size_t)c * 512 + lane * 8, d + c * 512);
    };

    stage(0, 0);
    stage(1, 1);

    float4v acc[4][4] = {};   // [tile][nf]
    for (int r = 0; r < n; r++) {
        int db = r & 1;
        // stage r complete when the newest 8 (stage r+1) may still be in flight
        if (r < n - 1) { asm volatile("s_waitcnt vmcnt(8)" ::: "memory"); }
        else           { asm volatile("s_waitcnt vmcnt(0)" ::: "memory"); }

        // B-frags for this kk (reused across the 4 M-tiles)
        short8 bfr[2][4];
        const unsigned short* bb = wbuf + db * 4096;
#pragma unroll
        for (int hh = 0; hh < 2; hh++)
#pragma unroll
            for (int nf = 0; nf < 4; nf++)
                bfr[hh][nf] = *(const short8*)(bb + (hh * 4 + nf) * 512 + lane * 8);

        // hv: 4 bf16 per tile (rows quad*4..+3), broadcast across l15
        bool bias = (r == 16);
        unsigned long long hu[4] = {0ull, 0ull, 0ull, 0ull};
        if (!bias) {
#pragma unroll
            for (int t = 0; t < 4; t++)
                hu[t] = *(const unsigned long long*)(hvl + (w * 16 + r) * 64 + t * 16 + quad * 4);
        }

        // all LDS reads done before overwriting buffer db with stage r+2
        asm volatile("s_waitcnt lgkmcnt(0)" ::: "memory");
        if (r + 2 < n) stage(r + 2, db);

#pragma unroll
        for (int t = 0; t < 4; t++) {
            float4v T[4];
#pragma unroll
            for (int nf = 0; nf < 4; nf++) {
                float4v z = {0.f, 0.f, 0.f, 0.f};
                T[nf] = __builtin_amdgcn_mfma_f32_16x16x32_bf16(afr[t][0], bfr[0][nf], z, 0, 0, 0);
            }
#pragma unroll
            for (int nf = 0; nf < 4; nf++)
                T[nf] = __builtin_amdgcn_mfma_f32_16x16x32_bf16(afr[t][1], bfr[1][nf], T[nf], 0, 0, 0);
#pragma unroll
            for (int rr = 0; rr < 4; rr++) {
                float hvv = bias ? 1.0f : bf2f((unsigned short)(hu[t] >> (16 * rr)));
#pragma unroll
                for (int nf = 0; nf < 4; nf++)
                    acc[t][nf][rr] += hvv * T[nf][rr];
            }
        }
    }

    // ---- cross-wave reduce (4 partials) + plain coalesced store ----
    __syncthreads();   // everyone done reading/staging LDS
    float* rp = red + w * 4224;                 // 64 rows x stride 66
#pragma unroll
    for (int t = 0; t < 4; t++)
#pragma unroll
        for (int nf = 0; nf < 4; nf++)
#pragma unroll
            for (int rr = 0; rr < 4; rr++)
                rp[(t * 16 + quad * 4 + rr) * 66 + nf * 16 + l15] = acc[t][nf][rr];
    __syncthreads();
    {
        int row = tid >> 2, cg = tid & 3;
        float s[16];
#pragma unroll
        for (int k = 0; k < 16; k++) {
            float v = 0.f;
#pragma unroll
            for (int ww = 0; ww < 4; ww++)
                v += red[ww * 4224 + row * 66 + cg * 16 + k];
            s[k] = v;
        }
        float* op = msgbuf + (size_t)(ebase + row) * 64 + cg * 16;
#pragma unroll
        for (int q = 0; q < 4; q++) {
            float4v v4 = { s[4 * q], s[4 * q + 1], s[4 * q + 2], s[4 * q + 3] };
            *(float4v*)(op + 4 * q) = v4;
        }
    }
}

// ===================== fused node update ===================================
// Gathers msgbuf rows via dst-sorted edge list (no atomics, no agg buffer).
__global__ __launch_bounds__(256) void k_node(
    const unsigned short* __restrict__ hb_in,
    const unsigned short* __restrict__ rootTf,
    const unsigned short* __restrict__ wcombf,
    const float* __restrict__ msgbuf, const int* __restrict__ off,
    const int* __restrict__ eorder,
    const float* __restrict__ counts,
    const float* __restrict__ conv_b,
    const float* __restrict__ bih, const float* __restrict__ bhh,
    unsigned short* __restrict__ hb_out)
{
    __shared__ unsigned short m_lds[64 * 72];
    __shared__ float aggl[64 * 68];
    int tid = threadIdx.x, w = tid >> 6, lane = tid & 63;
    int l15 = lane & 15, quad = lane >> 4;
    int node0 = blockIdx.x * 64;
    int row0 = w * 16;

    // ---- gather-aggregate: 4 threads per node x 16 cols ----
    {
        int nl = tid >> 2, cg = tid & 3;
        int nn = node0 + nl;
        int s0 = off[nn], s1 = off[nn + 1];
        float acc[16] = {};
        for (int sl = s0; sl < s1; sl++) {
            int e = eorder[sl];
            const float* mr = msgbuf + (size_t)e * 64 + cg * 16;
#pragma unroll
            for (int q = 0; q < 4; q++) {
                float4v v = *(const float4v*)(mr + 4 * q);
#pragma unroll
                for (int j = 0; j < 4; j++) acc[4 * q + j] += v[j];
            }
        }
#pragma unroll
        for (int k = 0; k < 16; k++) aggl[nl * 68 + cg * 16 + k] = acc[k];
    }
    __syncthreads();

    float4v acc1[4] = {};
    {
        short8 a1[2];
#pragma unroll
        for (int kb = 0; kb < 2; kb++)
            a1[kb] = *(const short8*)(hb_in + (size_t)(node0 + row0 + l15) * 64 + kb * 32 + quad * 8);
#pragma unroll
        for (int kb = 0; kb < 2; kb++)
#pragma unroll
            for (int nf = 0; nf < 4; nf++) {
                short8 b = *(const short8*)(rootTf + (size_t)((kb * 4 + nf) * 64 + lane) * 8);
                acc1[nf] = __builtin_amdgcn_mfma_f32_16x16x32_bf16(a1[kb], b, acc1[nf], 0, 0, 0);
            }
    }
#pragma unroll
    for (int rr = 0; rr < 4; rr++) {
        int nl = row0 + quad * 4 + rr;
        float cnt = counts[node0 + nl]; if (cnt < 1.f) cnt = 1.f;
        float rcp = 1.f / cnt;
#pragma unroll
        for (int nf = 0; nf < 4; nf++) {
            int c = nf * 16 + l15;
            float av = aggl[nl * 68 + c];
            float mv = av * rcp + acc1[nf][rr] + conv_b[c];
            m_lds[nl * 72 + c] = f2bf(mv > 0.f ? mv : 0.f);
        }
    }
    __syncthreads();

    float4v acc2[16] = {};
#pragma unroll
    for (int kb = 0; kb < 4; kb++) {
        short8 a2;
        if (kb < 2)
            a2 = *(const short8*)(m_lds + (row0 + l15) * 72 + kb * 32 + quad * 8);
        else
            a2 = *(const short8*)(hb_in + (size_t)(node0 + row0 + l15) * 64 + (kb - 2) * 32 + quad * 8);
#pragma unroll
        for (int nf = 0; nf < 16; nf++) {
            short8 b = *(const short8*)(wcombf + (size_t)((kb * 16 + nf) * 64 + lane) * 8);
            acc2[nf] = __builtin_amdgcn_mfma_f32_16x16x32_bf16(a2, b, acc2[nf], 0, 0, 0);
        }
    }

#pragma unroll
    for (int nf0 = 0; nf0 < 4; nf0++) {
        int c = nf0 * 16 + l15;
        float br = bih[c] + bhh[c];
        float bz = bih[64 + c] + bhh[64 + c];
        float bni = bih[128 + c], bnh = bhh[128 + c];
#pragma unroll
        for (int rr = 0; rr < 4; rr++) {
            int node = node0 + row0 + quad * 4 + rr;
            float gr = 1.f / (1.f + __expf(-(acc2[nf0][rr] + br)));
            float gz = 1.f / (1.f + __expf(-(acc2[nf0 + 4][rr] + bz)));
            float ng = tanhf(acc2[nf0 + 8][rr] + bni + gr * (acc2[nf0 + 12][rr] + bnh));
            float ho = bf2f(hb_in[(size_t)node * 64 + c]);
            float hn = (1.f - gz) * ng + gz * ho;
            hb_out[(size_t)node * 64 + c] = f2bf(hn);
        }
    }
}

// ===================== MFMA decoder ========================================
__global__ __launch_bounds__(256) void k_decoder(
    const unsigned short* __restrict__ hb, const int* __restrict__ ei,
    const float* __restrict__ ea,
    const unsigned short* __restrict__ wd1f, const unsigned short* __restrict__ wd2f,
    const float* __restrict__ bd2,
    const float* __restrict__ Wd3, const float* __restrict__ bd3,
    float* __restrict__ out)
{
    __shared__ unsigned short d1f[4][1024];  // per-wave: 2 frags x 512
    __shared__ float d2s[4][16 * 33];        // per-wave: 16 edges x 32 (+pad)
    int tid = threadIdx.x, w = tid >> 6, lane = tid & 63;
    int l15 = lane & 15, quad = lane >> 4;
    int ebase = blockIdx.x * 64 + w * 16;
    int e = ebase + l15;
    int src = ei[e], dst = ei[N_EDGES + e];

    short8 a[5];
#pragma unroll
    for (int kb = 0; kb < 2; kb++) {
        a[kb]     = *(const short8*)(hb + (size_t)src * 64 + kb * 32 + quad * 8);
        a[2 + kb] = *(const short8*)(hb + (size_t)dst * 64 + kb * 32 + quad * 8);
    }
    {
        union { short8 v; unsigned short u[8]; } tea;
#pragma unroll
        for (int j = 0; j < 8; j++) {
            float vv = 0.f;
            if (quad == 0) vv = (j < 5) ? ea[(size_t)e * 5 + j] : (j == 5 ? 1.f : 0.f);
            tea.u[j] = f2bf(vv);
        }
        a[4] = tea.v;
    }

    float4v acc1[4] = {};
#pragma unroll
    for (int kb = 0; kb < 5; kb++)
#pragma unroll
        for (int nf = 0; nf < 4; nf++) {
            short8 b = *(const short8*)(wd1f + (size_t)((kb * 4 + nf) * 64 + lane) * 8);
            acc1[nf] = __builtin_amdgcn_mfma_f32_16x16x32_bf16(a[kb], b, acc1[nf], 0, 0, 0);
        }
#pragma unroll
    for (int nf = 0; nf < 4; nf++) {
        int kbp = nf >> 1;
        int lanep_hi = ((nf & 1) * 2 + (l15 >> 3)) * 16;
        int jp = l15 & 7;
#pragma unroll
        for (int r = 0; r < 4; r++) {
            float v = acc1[nf][r];
            d1f[w][kbp * 512 + (lanep_hi + quad * 4 + r) * 8 + jp] = f2bf(v > 0.f ? v : 0.f);
        }
    }
    float4v acc2[2] = {};
#pragma unroll
    for (int kb = 0; kb < 2; kb++) {
        short8 a2 = *(const short8*)(&d1f[w][kb * 512 + lane * 8]);
#pragma unroll
        for (int nf = 0; nf < 2; nf++) {
            short8 b = *(const short8*)(wd2f + (size_t)((kb * 2 + nf) * 64 + lane) * 8);
            acc2[nf] = __builtin_amdgcn_mfma_f32_16x16x32_bf16(a2, b, acc2[nf], 0, 0, 0);
        }
    }
#pragma unroll
    for (int nf = 0; nf < 2; nf++) {
        int c = nf * 16 + l15;
        float bias = bd2[c];
#pragma unroll
        for (int r = 0; r < 4; r++) {
            float v = acc2[nf][r] + bias;
            d2s[w][(quad * 4 + r) * 33 + c] = v > 0.f ? v : 0.f;
        }
    }
    {
        int e_l = lane >> 2, t = lane & 3;
        float s = bd3[t];
        const float* w3 = Wd3 + t * 32;
        const float* dr = &d2s[w][e_l * 33];
#pragma unroll
        for (int k = 0; k < 32; k++) s += w3[k] * dr[k];
        out[(size_t)(ebase + e_l) * 4 + t] = s;
    }
}

extern "C" void kernel_launch(void* const* d_in, const int* in_sizes, int n_in,
                              void* d_out, int out_size, void* d_ws, size_t ws_size,
                              hipStream_t stream)
{
    const float* x      = (const float*)d_in[0];
    const int*   ei     = (const int*)d_in[1];
    const float* ea     = (const float*)d_in[2];
    const float* u      = (const float*)d_in[3];
    const float* Wp     = (const float*)d_in[4];
    const float* bp     = (const float*)d_in[5];
    const float* We1    = (const float*)d_in[6];
    const float* be1    = (const float*)d_in[7];
    const float* We2    = (const float*)d_in[8];
    const float* be2    = (const float*)d_in[9];
    const float* root   = (const float*)d_in[10];
    const float* conv_b = (const float*)d_in[11];
    const float* Wih    = (const float*)d_in[12];
    const float* bih    = (const float*)d_in[13];
    const float* Whh    = (const float*)d_in[14];
    const float* bhh    = (const float*)d_in[15];
    const float* Wd1    = (const float*)d_in[16];
    const float* bd1    = (const float*)d_in[17];
    const float* Wd2    = (const float*)d_in[18];
    const float* bd2    = (const float*)d_in[19];
    const float* Wd3    = (const float*)d_in[20];
    const float* bd3    = (const float*)d_in[21];
    float* out = (float*)d_out;

    char* ws = (char*)d_ws;
    size_t off_b = 0;
    auto take = [&](size_t bytes) -> char* {
        char* p = ws + off_b; off_b = (off_b + bytes + 255) & ~(size_t)255; return p;
    };
    unsigned short* hb     = (unsigned short*)take((size_t)N_NODES * 64 * 2);
    unsigned short* hidT   = (unsigned short*)take((size_t)N_EDGES * 64 * 2);
    float*          msgbuf = (float*)take((size_t)N_EDGES * 64 * 4);
    float*          cnts   = (float*)take((size_t)N_NODES * 4);
    int*            off    = (int*)take((size_t)(N_NODES + 1) * 4);
    int*            woff   = (int*)take((size_t)N_NODES * 4);
    int*            eorder = (int*)take((size_t)N_EDGES * 4);
    unsigned short* w2tf   = (unsigned short*)take((size_t)66 * 4096 * 2);  // +1 pad blk
    unsigned short* rootTf = (unsigned short*)take((size_t)4096 * 2);
    unsigned short* wcombf = (unsigned short*)take((size_t)32768 * 2);
    unsigned short* wd1f   = (unsigned short*)take((size_t)10240 * 2);
    unsigned short* wd2f   = (unsigned short*)take((size_t)2048 * 2);
    (void)ws_size;

    k_setup<<<17648, 256, 0, stream>>>(root, Wih, Whh, We2, be2, Wd1, bd1, Wd2,
                                       x, u, Wp, bp, ea, We1, be1,
                                       rootTf, wcombf, w2tf, wd1f, wd2f,
                                       hb, hidT, cnts);
    k_counts<<<128, 256, 0, stream>>>(ei, cnts);
    k_scan<<<1, 1024, 0, stream>>>(cnts, off, woff);
    k_scatter<<<128, 256, 0, stream>>>(ei, woff, eorder);

    for (int s = 0; s < STEPS; s++) {
        k_msg_fused<<<N_EDGES / 64, 256, 0, stream>>>(hidT, hb, w2tf, ei, msgbuf);
        k_node<<<N_NODES / 64, 256, 0, stream>>>(hb, rootTf, wcombf, msgbuf, off,
                                                 eorder, cnts, conv_b, bih, bhh, hb);
    }
    k_decoder<<<N_EDGES / 64, 256, 0, stream>>>(hb, ei, ea, wd1f, wd2f, bd2,
                                                Wd3, bd3, out);
}